// Round 1
// baseline (508.207 us; speedup 1.0000x reference)
//
#include <hip/hip_runtime.h>
#include <hip/hip_bf16.h>
#include <math.h>

// GAT x3 + LayerNorm for MI355X (gfx950). All f32.
// Pipeline per launch:
//   1. memset deg/asum/fill
//   2. deg_kernel: in-degree + edge_attr sum per dst (atomics)
//   3. scan_kernel: row_ptr = exclusive scan of (deg+1)  [single block]
//   4. scatter_kernel: CSR fill of original edges (atomic slot counter)
//   5. selfloop_kernel: append self loop last in each row, attr = mean
//   6. wedot_kernel: per-head scalar Σ We*ae (EDIM==1 collapse)
//   per layer: gemm -> dots (al_s/al_d) -> aggregation (online softmax,
//   fused bias+ELU; layer2 fuses LayerNorm and writes d_out).

__device__ __forceinline__ float wave_sum(float v) {
#pragma unroll
  for (int off = 32; off > 0; off >>= 1) v += __shfl_xor(v, off, 64);
  return v;
}

__global__ void deg_kernel(const int* __restrict__ dst, const float* __restrict__ eattr,
                           int* __restrict__ deg, float* __restrict__ asum, int E) {
  int e = blockIdx.x * 256 + threadIdx.x;
  if (e >= E) return;
  int d = dst[e];
  atomicAdd(&deg[d], 1);
  atomicAdd(&asum[d], eattr[e]);
}

// exclusive scan of (deg[i]+1) over n entries -> row_ptr[0..n]
__global__ __launch_bounds__(1024) void scan_kernel(const int* __restrict__ deg,
                                                    int* __restrict__ row_ptr, int n) {
  __shared__ int lds[1024];
  __shared__ int carry;
  if (threadIdx.x == 0) carry = 0;
  __syncthreads();
  for (int base = 0; base < n; base += 1024) {
    int i = base + (int)threadIdx.x;
    int v = (i < n) ? (deg[i] + 1) : 0;
    lds[threadIdx.x] = v;
    __syncthreads();
    for (int off = 1; off < 1024; off <<= 1) {
      int t = (threadIdx.x >= (unsigned)off) ? lds[threadIdx.x - off] : 0;
      __syncthreads();
      lds[threadIdx.x] += t;
      __syncthreads();
    }
    if (i < n) row_ptr[i] = carry + lds[threadIdx.x] - v;
    __syncthreads();
    if (threadIdx.x == 0) carry += lds[1023];
    __syncthreads();
  }
  if (threadIdx.x == 0) row_ptr[n] = carry;
}

__global__ void scatter_kernel(const int* __restrict__ src, const int* __restrict__ dst,
                               const float* __restrict__ eattr, const int* __restrict__ row_ptr,
                               int* __restrict__ fill, int* __restrict__ col_idx,
                               float* __restrict__ evalv, int E) {
  int e = blockIdx.x * 256 + threadIdx.x;
  if (e >= E) return;
  int d = dst[e];
  int pos = row_ptr[d] + atomicAdd(&fill[d], 1);
  col_idx[pos] = src[e];
  evalv[pos] = eattr[e];
}

__global__ void selfloop_kernel(const int* __restrict__ deg, const float* __restrict__ asum,
                                const int* __restrict__ row_ptr, int* __restrict__ col_idx,
                                float* __restrict__ evalv, int n) {
  int i = blockIdx.x * 256 + threadIdx.x;
  if (i >= n) return;
  int d = deg[i];
  int pos = row_ptr[i] + d;  // self loop is the last slot in the row
  col_idx[pos] = i;
  evalv[pos] = asum[i] / fmaxf((float)d, 1.f);
}

// wedot[0..3]=layer0 heads, [4..7]=layer1 heads, [8]=layer2
__global__ void wedot_kernel(const float* __restrict__ We0, const float* __restrict__ ae0,
                             const float* __restrict__ We1, const float* __restrict__ ae1,
                             const float* __restrict__ We2, const float* __restrict__ ae2,
                             float* __restrict__ wedot) {
  int c = threadIdx.x;  // 0..63
  for (int h = 0; h < 4; h++) {
    float v = wave_sum(We0[h * 64 + c] * ae0[h * 64 + c]);
    if (c == 0) wedot[h] = v;
  }
  for (int h = 0; h < 4; h++) {
    float v = wave_sum(We1[h * 64 + c] * ae1[h * 64 + c]);
    if (c == 0) wedot[4 + h] = v;
  }
  float v = wave_sum(We2[c] * ae2[c]);
  if (c == 0) wedot[8] = v;
}

// out[n,M] = in[n,K] @ W[K,M]. Block: 16 rows x M cols; 256 threads.
// Thread: 4 rows x (M/64) cols. Rows staged in LDS (float4); LDS reads are
// wave-uniform -> broadcast, conflict-free.
template <int K, int M>
__global__ __launch_bounds__(256) void gemm_kernel(const float* __restrict__ in,
                                                   const float* __restrict__ W,
                                                   float* __restrict__ out, int n) {
  constexpr int CT = M / 64;
  constexpr int T = 4;
  constexpr int ROWS = 16;
  __shared__ float4 lds[ROWS * K / 4];
  int row0 = blockIdx.x * ROWS;
  int tid = threadIdx.x;
  int total4 = ROWS * K / 4;
  const float4* in4 = (const float4*)(in + (size_t)row0 * K);
  if (row0 + ROWS <= n) {
    for (int i = tid; i < total4; i += 256) lds[i] = in4[i];
  } else {
    for (int i = tid; i < total4; i += 256) {
      int r = row0 + (i * 4) / K;
      float4 z = make_float4(0.f, 0.f, 0.f, 0.f);
      lds[i] = (r < n) ? in4[i] : z;
    }
  }
  __syncthreads();
  int c0 = tid & 63;
  int rg = tid >> 6;
  float acc[T][CT];
#pragma unroll
  for (int t = 0; t < T; t++)
#pragma unroll
    for (int c = 0; c < CT; c++) acc[t][c] = 0.f;

  for (int k4 = 0; k4 < K; k4 += 4) {
    float4 xr[T];
#pragma unroll
    for (int t = 0; t < T; t++) xr[t] = lds[(rg * T + t) * (K / 4) + (k4 >> 2)];
#pragma unroll
    for (int kk = 0; kk < 4; kk++) {
#pragma unroll
      for (int c = 0; c < CT; c++) {
        float w = W[(size_t)(k4 + kk) * M + c0 + 64 * c];
#pragma unroll
        for (int t = 0; t < T; t++) {
          float xv = ((const float*)&xr[t])[kk];
          acc[t][c] = fmaf(xv, w, acc[t][c]);
        }
      }
    }
  }
#pragma unroll
  for (int t = 0; t < T; t++) {
    int r = row0 + rg * T + t;
    if (r < n) {
#pragma unroll
      for (int c = 0; c < CT; c++) out[(size_t)r * M + c0 + 64 * c] = acc[t][c];
    }
  }
}

// al_s[n,H], al_d[n,H] from h[n,H*64]; one wave per (node, head)
template <int H>
__global__ __launch_bounds__(256) void dots_kernel(const float* __restrict__ B,
                                                   const float* __restrict__ a_s,
                                                   const float* __restrict__ a_d,
                                                   float* __restrict__ al_s,
                                                   float* __restrict__ al_d, int n) {
  int wid = blockIdx.x * 4 + (threadIdx.x >> 6);
  int c = threadIdx.x & 63;
  if (wid >= n * H) return;
  int node = wid / H;
  int h = wid % H;
  float v = B[(size_t)node * (H * 64) + h * 64 + c];
  float s = v * a_s[h * 64 + c];
  float d = v * a_d[h * 64 + c];
#pragma unroll
  for (int off = 32; off > 0; off >>= 1) {
    s += __shfl_xor(s, off, 64);
    d += __shfl_xor(d, off, 64);
  }
  if (c == 0) {
    al_s[wid] = s;
    al_d[wid] = d;
  }
}

// H=4 aggregation with online softmax; bias + ELU fused. One block per node,
// 4 waves = 4 heads.
__global__ __launch_bounds__(256) void agg4_kernel(
    const int* __restrict__ row_ptr, const int* __restrict__ col_idx,
    const float* __restrict__ evalv, const float* __restrict__ al_s,
    const float* __restrict__ al_d, const float* __restrict__ wedot,
    const float* __restrict__ B, const float* __restrict__ bias,
    float* __restrict__ out, int n) {
  int node = blockIdx.x;
  if (node >= n) return;
  int hh = threadIdx.x >> 6;
  int c = threadIdx.x & 63;
  float wd = wedot[hh];
  float adn = al_d[node * 4 + hh];
  int beg = row_ptr[node], end = row_ptr[node + 1];
  float m = -1e30f, den = 0.f, acc = 0.f;
  for (int e = beg; e < end; e++) {
    int s = col_idx[e];
    float a = al_s[s * 4 + hh] + adn + evalv[e] * wd;
    a = fmaxf(a, 0.2f * a);  // leaky_relu(a, 0.2)
    float nm = fmaxf(m, a);
    float sc = __expf(m - nm);
    float ea = __expf(a - nm);
    float hv = B[(size_t)s * 256 + hh * 64 + c];
    den = den * sc + ea;
    acc = fmaf(ea, hv, acc * sc);
    m = nm;
  }
  float o = acc / (den + 1e-16f) + bias[hh * 64 + c];
  o = o > 0.f ? o : expm1f(o);  // ELU
  out[(size_t)node * 256 + threadIdx.x] = o;
}

// H=1 aggregation + bias + LayerNorm fused; one wave per node (64 channels).
__global__ __launch_bounds__(256) void agg_ln_kernel(
    const int* __restrict__ row_ptr, const int* __restrict__ col_idx,
    const float* __restrict__ evalv, const float* __restrict__ al_s,
    const float* __restrict__ al_d, const float* __restrict__ wedot,
    const float* __restrict__ B, const float* __restrict__ bias,
    const float* __restrict__ ln_g, const float* __restrict__ ln_b,
    float* __restrict__ out, int n) {
  int node = blockIdx.x * 4 + (threadIdx.x >> 6);
  int c = threadIdx.x & 63;
  if (node >= n) return;
  float wd = wedot[0];
  float adn = al_d[node];
  int beg = row_ptr[node], end = row_ptr[node + 1];
  float m = -1e30f, den = 0.f, acc = 0.f;
  for (int e = beg; e < end; e++) {
    int s = col_idx[e];
    float a = al_s[s] + adn + evalv[e] * wd;
    a = fmaxf(a, 0.2f * a);
    float nm = fmaxf(m, a);
    float sc = __expf(m - nm);
    float ea = __expf(a - nm);
    float hv = B[(size_t)s * 64 + c];
    den = den * sc + ea;
    acc = fmaf(ea, hv, acc * sc);
    m = nm;
  }
  float o = acc / (den + 1e-16f) + bias[c];
  float mu = wave_sum(o) * (1.f / 64.f);
  float dv = o - mu;
  float var = wave_sum(dv * dv) * (1.f / 64.f);
  out[(size_t)node * 64 + c] = dv * rsqrtf(var + 1e-5f) * ln_g[c] + ln_b[c];
}

extern "C" void kernel_launch(void* const* d_in, const int* in_sizes, int n_in,
                              void* d_out, int out_size, void* d_ws, size_t ws_size,
                              hipStream_t stream) {
  const float* x = (const float*)d_in[0];
  const int* ei = (const int*)d_in[1];
  const float* eattr = (const float*)d_in[2];
  const float* W0 = (const float*)d_in[3];
  const float* as0 = (const float*)d_in[4];
  const float* ad0 = (const float*)d_in[5];
  const float* We0 = (const float*)d_in[6];
  const float* ae0 = (const float*)d_in[7];
  const float* b0 = (const float*)d_in[8];
  const float* W1 = (const float*)d_in[9];
  const float* as1 = (const float*)d_in[10];
  const float* ad1 = (const float*)d_in[11];
  const float* We1 = (const float*)d_in[12];
  const float* ae1 = (const float*)d_in[13];
  const float* b1 = (const float*)d_in[14];
  const float* W2 = (const float*)d_in[15];
  const float* as2 = (const float*)d_in[16];
  const float* ad2 = (const float*)d_in[17];
  const float* We2 = (const float*)d_in[18];
  const float* ae2 = (const float*)d_in[19];
  const float* b2 = (const float*)d_in[20];
  const float* lng = (const float*)d_in[21];
  const float* lnb = (const float*)d_in[22];
  float* outp = (float*)d_out;

  const int N = in_sizes[0] / 16;
  const int E = in_sizes[1] / 2;
  const int* srcv = ei;
  const int* dstv = ei + E;

  // workspace carve-up (256B aligned)
  char* w = (char*)d_ws;
  size_t off = 0;
  auto alloc = [&](size_t bytes) -> void* {
    void* p = w + off;
    off += (bytes + 255) & ~(size_t)255;
    return p;
  };
  int* deg = (int*)alloc((size_t)N * 4);
  float* asum = (float*)alloc((size_t)N * 4);
  int* fill = (int*)alloc((size_t)N * 4);
  size_t zero_bytes = off;  // deg+asum+fill zeroed in one memset
  int* row_ptr = (int*)alloc((size_t)(N + 1) * 4);
  int* col_idx = (int*)alloc((size_t)(E + N) * 4);
  float* evalv = (float*)alloc((size_t)(E + N) * 4);
  float* wedot = (float*)alloc(16 * 4);
  float* al_s = (float*)alloc((size_t)N * 4 * 4);
  float* al_d = (float*)alloc((size_t)N * 4 * 4);
  float* bufA = (float*)alloc((size_t)N * 256 * 4);
  float* bufB = (float*)alloc((size_t)N * 256 * 4);
  (void)ws_size;

  hipMemsetAsync(d_ws, 0, zero_bytes, stream);

  int gE = (E + 255) / 256;
  int gN = (N + 255) / 256;
  deg_kernel<<<gE, 256, 0, stream>>>(dstv, eattr, deg, asum, E);
  scan_kernel<<<1, 1024, 0, stream>>>(deg, row_ptr, N);
  scatter_kernel<<<gE, 256, 0, stream>>>(srcv, dstv, eattr, row_ptr, fill, col_idx, evalv, E);
  selfloop_kernel<<<gN, 256, 0, stream>>>(deg, asum, row_ptr, col_idx, evalv, N);
  wedot_kernel<<<1, 64, 0, stream>>>(We0, ae0, We1, ae1, We2, ae2, wedot);

  int gGemm = (N + 15) / 16;
  int gDots4 = (N * 4 + 3) / 4;  // = N
  int gDots1 = (N + 3) / 4;

  // ---- layer 0: x[N,16] @ W0 -> bufB[N,256]
  gemm_kernel<16, 256><<<gGemm, 256, 0, stream>>>(x, W0, bufB, N);
  dots_kernel<4><<<gDots4, 256, 0, stream>>>(bufB, as0, ad0, al_s, al_d, N);
  agg4_kernel<<<N, 256, 0, stream>>>(row_ptr, col_idx, evalv, al_s, al_d, wedot,
                                     bufB, b0, bufA, N);

  // ---- layer 1: bufA[N,256] @ W1 -> bufB[N,256]
  gemm_kernel<256, 256><<<gGemm, 256, 0, stream>>>(bufA, W1, bufB, N);
  dots_kernel<4><<<gDots4, 256, 0, stream>>>(bufB, as1, ad1, al_s, al_d, N);
  agg4_kernel<<<N, 256, 0, stream>>>(row_ptr, col_idx, evalv, al_s, al_d, wedot + 4,
                                     bufB, b1, bufA, N);

  // ---- layer 2: bufA[N,256] @ W2 -> bufB[N,64]; agg + LayerNorm -> d_out
  gemm_kernel<256, 64><<<gGemm, 256, 0, stream>>>(bufA, W2, bufB, N);
  dots_kernel<1><<<gDots1, 256, 0, stream>>>(bufB, as2, ad2, al_s, al_d, N);
  agg_ln_kernel<<<gDots1, 256, 0, stream>>>(row_ptr, col_idx, evalv, al_s, al_d,
                                            wedot + 8, bufB, b2, lng, lnb, outp, N);
}

// Round 2
// 440.038 us; speedup vs baseline: 1.1549x; 1.1549x over previous
//
#include <hip/hip_runtime.h>
#include <hip/hip_bf16.h>
#include <math.h>

// GAT x3 + LayerNorm for MI355X (gfx950). All f32.
// R2: edge-parallel exp weights (softmax max cancels), float4 one-wave-per-node
// aggregation, dots fused into GEMM epilogue, 32-row GEMM tiles, shfl-scan.

__device__ __forceinline__ float wave_sum(float v) {
#pragma unroll
  for (int off = 32; off > 0; off >>= 1) v += __shfl_xor(v, off, 64);
  return v;
}

__global__ void deg_kernel(const int* __restrict__ dst, const float* __restrict__ eattr,
                           int* __restrict__ deg, float* __restrict__ asum, int E) {
  int e = blockIdx.x * 256 + threadIdx.x;
  if (e >= E) return;
  int d = dst[e];
  atomicAdd(&deg[d], 1);
  atomicAdd(&asum[d], eattr[e]);
}

// row_ptr = exclusive scan of (deg[i]+1); single block, shfl-based.
__global__ __launch_bounds__(1024) void scan_kernel(const int* __restrict__ deg,
                                                    int* __restrict__ row_ptr, int n) {
  __shared__ int wexc[16];
  __shared__ int carry, chunk_tot;
  int tid = threadIdx.x, wid = tid >> 6, lane = tid & 63;
  if (tid == 0) carry = 0;
  __syncthreads();
  for (int base = 0; base < n; base += 1024) {
    int i = base + tid;
    int v = (i < n) ? (deg[i] + 1) : 0;
    int sc = v;  // inclusive wave scan
#pragma unroll
    for (int off = 1; off < 64; off <<= 1) {
      int t = __shfl_up(sc, off, 64);
      if (lane >= off) sc += t;
    }
    if (lane == 63) wexc[wid] = sc;
    __syncthreads();
    if (tid == 0) {
      int run = 0;
#pragma unroll
      for (int wI = 0; wI < 16; wI++) { int t = wexc[wI]; wexc[wI] = run; run += t; }
      chunk_tot = run;
    }
    __syncthreads();
    if (i < n) row_ptr[i] = carry + wexc[wid] + sc - v;
    __syncthreads();
    if (tid == 0) carry += chunk_tot;
    __syncthreads();
  }
  if (threadIdx.x == 0) row_ptr[n] = carry;
}

__global__ void scatter_kernel(const int* __restrict__ src, const int* __restrict__ dst,
                               const float* __restrict__ eattr, const int* __restrict__ row_ptr,
                               int* __restrict__ fill, int* __restrict__ col_idx,
                               int* __restrict__ dstpos, float* __restrict__ evalv, int E) {
  int e = blockIdx.x * 256 + threadIdx.x;
  if (e >= E) return;
  int d = dst[e];
  int pos = row_ptr[d] + atomicAdd(&fill[d], 1);
  col_idx[pos] = src[e];
  dstpos[pos] = d;
  evalv[pos] = eattr[e];
}

__global__ void selfloop_kernel(const int* __restrict__ deg, const float* __restrict__ asum,
                                const int* __restrict__ row_ptr, int* __restrict__ col_idx,
                                int* __restrict__ dstpos, float* __restrict__ evalv, int n) {
  int i = blockIdx.x * 256 + threadIdx.x;
  if (i >= n) return;
  int d = deg[i];
  int pos = row_ptr[i] + d;  // self loop last in row
  col_idx[pos] = i;
  dstpos[pos] = i;
  evalv[pos] = asum[i] / fmaxf((float)d, 1.f);
}

// wedot[0..3]=layer0 heads, [4..7]=layer1 heads, [8]=layer2
__global__ void wedot_kernel(const float* __restrict__ We0, const float* __restrict__ ae0,
                             const float* __restrict__ We1, const float* __restrict__ ae1,
                             const float* __restrict__ We2, const float* __restrict__ ae2,
                             float* __restrict__ wedot) {
  int c = threadIdx.x;  // 0..63
  for (int h = 0; h < 4; h++) {
    float v = wave_sum(We0[h * 64 + c] * ae0[h * 64 + c]);
    if (c == 0) wedot[h] = v;
  }
  for (int h = 0; h < 4; h++) {
    float v = wave_sum(We1[h * 64 + c] * ae1[h * 64 + c]);
    if (c == 0) wedot[4 + h] = v;
  }
  float v = wave_sum(We2[c] * ae2[c]);
  if (c == 0) wedot[8] = v;
}

// out[n,M] = in[n,K] @ W[K,M], plus fused per-head attention dots:
// al_s[r,h] = sum_c out[r,h*64+c]*a_s[h,c]  (head slice == col-tile slot).
// Block: 32 rows x M cols, 256 threads (4 waves x 8 rows), thread: 8r x M/64 c.
template <int K, int M, int H>
__global__ __launch_bounds__(256) void gemm_dots_kernel(
    const float* __restrict__ in, const float* __restrict__ W,
    const float* __restrict__ a_s, const float* __restrict__ a_d,
    float* __restrict__ out, float* __restrict__ al_s, float* __restrict__ al_d, int n) {
  constexpr int CT = M / 64;
  constexpr int ROWS = 32;
  constexpr int T = 8;
  static_assert(CT == H, "head slice must equal col-tile slot");
  __shared__ float4 lds[ROWS * K / 4];
  int row0 = blockIdx.x * ROWS;
  int tid = threadIdx.x;
  int total4 = ROWS * K / 4;
  const float4* in4 = (const float4*)(in + (size_t)row0 * K);
  if (row0 + ROWS <= n) {
    for (int i = tid; i < total4; i += 256) lds[i] = in4[i];
  } else {
    float4 z = make_float4(0.f, 0.f, 0.f, 0.f);
    for (int i = tid; i < total4; i += 256) {
      int r = row0 + (i * 4) / K;
      lds[i] = (r < n) ? in4[i] : z;
    }
  }
  __syncthreads();
  int c0 = tid & 63;
  int rg = tid >> 6;
  float acc[T][CT];
#pragma unroll
  for (int t = 0; t < T; t++)
#pragma unroll
    for (int c = 0; c < CT; c++) acc[t][c] = 0.f;

  for (int k4 = 0; k4 < K; k4 += 4) {
    float wv[4][CT];
#pragma unroll
    for (int kk = 0; kk < 4; kk++)
#pragma unroll
      for (int c = 0; c < CT; c++) wv[kk][c] = W[(size_t)(k4 + kk) * M + c0 + 64 * c];
#pragma unroll
    for (int t = 0; t < T; t++) {
      float4 xv = lds[(rg * T + t) * (K / 4) + (k4 >> 2)];
      const float* xs = (const float*)&xv;
#pragma unroll
      for (int kk = 0; kk < 4; kk++)
#pragma unroll
        for (int c = 0; c < CT; c++) acc[t][c] = fmaf(xs[kk], wv[kk][c], acc[t][c]);
    }
  }
#pragma unroll
  for (int t = 0; t < T; t++) {
    int r = row0 + rg * T + t;
    if (r < n) {
#pragma unroll
      for (int c = 0; c < CT; c++) out[(size_t)r * M + c0 + 64 * c] = acc[t][c];
#pragma unroll
      for (int h = 0; h < H; h++) {
        float vs = acc[t][h] * a_s[h * 64 + c0];
        float vd = acc[t][h] * a_d[h * 64 + c0];
#pragma unroll
        for (int off = 32; off > 0; off >>= 1) {
          vs += __shfl_xor(vs, off, 64);
          vd += __shfl_xor(vd, off, 64);
        }
        if (c0 == 0) {
          al_s[(size_t)r * H + h] = vs;
          al_d[(size_t)r * H + h] = vd;
        }
      }
    }
  }
}

// Edge-parallel softmax weights: ew[p,h] = exp(leakyrelu(als[s]+ald[d]+ev*wd)).
// Max-subtraction cancels in the segment softmax ratio; magnitudes here are
// O(1) so exp never overflows (clamped at 30 for safety).
template <int H>
__global__ void ew_kernel(const int* __restrict__ col_idx, const int* __restrict__ dstpos,
                          const float* __restrict__ evalv, const float* __restrict__ al_s,
                          const float* __restrict__ al_d, const float* __restrict__ wedot,
                          float* __restrict__ ew, int P) {
  int p = blockIdx.x * 256 + threadIdx.x;
  if (p >= P) return;
  int s = col_idx[p];
  int d = dstpos[p];
  float ev = evalv[p];
#pragma unroll
  for (int h = 0; h < H; h++) {
    float a = al_s[(size_t)s * H + h] + al_d[(size_t)d * H + h] + ev * wedot[h];
    a = fmaxf(a, 0.2f * a);
    a = fminf(a, 30.f);
    ew[(size_t)p * H + h] = __expf(a);
  }
}

// H=4 aggregation: one wave per node, lane c holds channels 4c..4c+3
// (head = c>>4). Full B row fetched as one dwordx4/lane. bias+ELU fused.
__global__ __launch_bounds__(256) void agg4_kernel(
    const int* __restrict__ row_ptr, const int* __restrict__ col_idx,
    const float* __restrict__ ew, const float* __restrict__ B,
    const float* __restrict__ bias, float* __restrict__ out, int n) {
  int node = blockIdx.x * 4 + (threadIdx.x >> 6);
  int c = threadIdx.x & 63;
  if (node >= n) return;
  int h4 = c >> 4;
  int beg = row_ptr[node], end = row_ptr[node + 1];
  const float4* Bp = (const float4*)B;
  float4 acc = make_float4(0.f, 0.f, 0.f, 0.f);
  float den = 0.f;
  int s = col_idx[beg];
  float w = ew[(size_t)beg * 4 + h4];
  float4 bv = Bp[(size_t)s * 64 + c];
  for (int e = beg + 1; e < end; e++) {
    int s2 = col_idx[e];
    float w2 = ew[(size_t)e * 4 + h4];
    float4 bv2 = Bp[(size_t)s2 * 64 + c];
    den += w;
    acc.x = fmaf(w, bv.x, acc.x);
    acc.y = fmaf(w, bv.y, acc.y);
    acc.z = fmaf(w, bv.z, acc.z);
    acc.w = fmaf(w, bv.w, acc.w);
    w = w2;
    bv = bv2;
  }
  den += w;
  acc.x = fmaf(w, bv.x, acc.x);
  acc.y = fmaf(w, bv.y, acc.y);
  acc.z = fmaf(w, bv.z, acc.z);
  acc.w = fmaf(w, bv.w, acc.w);
  float inv = 1.f / (den + 1e-16f);
  float4 b4 = ((const float4*)bias)[c];
  float4 o;
  o.x = acc.x * inv + b4.x;
  o.y = acc.y * inv + b4.y;
  o.z = acc.z * inv + b4.z;
  o.w = acc.w * inv + b4.w;
  o.x = o.x > 0.f ? o.x : expm1f(o.x);
  o.y = o.y > 0.f ? o.y : expm1f(o.y);
  o.z = o.z > 0.f ? o.z : expm1f(o.z);
  o.w = o.w > 0.f ? o.w : expm1f(o.w);
  ((float4*)out)[(size_t)node * 64 + c] = o;
}

// H=1 aggregation + bias + LayerNorm fused; one wave per node (64 channels).
__global__ __launch_bounds__(256) void agg_ln_kernel(
    const int* __restrict__ row_ptr, const int* __restrict__ col_idx,
    const float* __restrict__ ew, const float* __restrict__ B,
    const float* __restrict__ bias, const float* __restrict__ ln_g,
    const float* __restrict__ ln_b, float* __restrict__ out, int n) {
  int node = blockIdx.x * 4 + (threadIdx.x >> 6);
  int c = threadIdx.x & 63;
  if (node >= n) return;
  int beg = row_ptr[node], end = row_ptr[node + 1];
  float acc = 0.f, den = 0.f;
  int s = col_idx[beg];
  float w = ew[beg];
  float bv = B[(size_t)s * 64 + c];
  for (int e = beg + 1; e < end; e++) {
    int s2 = col_idx[e];
    float w2 = ew[e];
    float bv2 = B[(size_t)s2 * 64 + c];
    den += w;
    acc = fmaf(w, bv, acc);
    w = w2;
    bv = bv2;
  }
  den += w;
  acc = fmaf(w, bv, acc);
  float o = acc / (den + 1e-16f) + bias[c];
  float mu = wave_sum(o) * (1.f / 64.f);
  float dv = o - mu;
  float var = wave_sum(dv * dv) * (1.f / 64.f);
  out[(size_t)node * 64 + c] = dv * rsqrtf(var + 1e-5f) * ln_g[c] + ln_b[c];
}

extern "C" void kernel_launch(void* const* d_in, const int* in_sizes, int n_in,
                              void* d_out, int out_size, void* d_ws, size_t ws_size,
                              hipStream_t stream) {
  const float* x = (const float*)d_in[0];
  const int* ei = (const int*)d_in[1];
  const float* eattr = (const float*)d_in[2];
  const float* W0 = (const float*)d_in[3];
  const float* as0 = (const float*)d_in[4];
  const float* ad0 = (const float*)d_in[5];
  const float* We0 = (const float*)d_in[6];
  const float* ae0 = (const float*)d_in[7];
  const float* b0 = (const float*)d_in[8];
  const float* W1 = (const float*)d_in[9];
  const float* as1 = (const float*)d_in[10];
  const float* ad1 = (const float*)d_in[11];
  const float* We1 = (const float*)d_in[12];
  const float* ae1 = (const float*)d_in[13];
  const float* b1 = (const float*)d_in[14];
  const float* W2 = (const float*)d_in[15];
  const float* as2 = (const float*)d_in[16];
  const float* ad2 = (const float*)d_in[17];
  const float* We2 = (const float*)d_in[18];
  const float* ae2 = (const float*)d_in[19];
  const float* b2 = (const float*)d_in[20];
  const float* lng = (const float*)d_in[21];
  const float* lnb = (const float*)d_in[22];
  float* outp = (float*)d_out;

  const int N = in_sizes[0] / 16;
  const int E = in_sizes[1] / 2;
  const int P = E + N;  // edges incl. self loops
  const int* srcv = ei;
  const int* dstv = ei + E;

  char* w = (char*)d_ws;
  size_t off = 0;
  auto alloc = [&](size_t bytes) -> void* {
    void* p = w + off;
    off += (bytes + 255) & ~(size_t)255;
    return p;
  };
  int* deg = (int*)alloc((size_t)N * 4);
  float* asum = (float*)alloc((size_t)N * 4);
  int* fill = (int*)alloc((size_t)N * 4);
  size_t zero_bytes = off;  // deg+asum+fill zeroed in one memset
  int* row_ptr = (int*)alloc((size_t)(N + 1) * 4);
  int* col_idx = (int*)alloc((size_t)P * 4);
  int* dstpos = (int*)alloc((size_t)P * 4);
  float* evalv = (float*)alloc((size_t)P * 4);
  float* wedot = (float*)alloc(16 * 4);
  float* al_s = (float*)alloc((size_t)N * 4 * 4);
  float* al_d = (float*)alloc((size_t)N * 4 * 4);
  float* ewb = (float*)alloc((size_t)P * 4 * 4);
  float* bufA = (float*)alloc((size_t)N * 256 * 4);
  float* bufB = (float*)alloc((size_t)N * 256 * 4);
  (void)ws_size;

  hipMemsetAsync(d_ws, 0, zero_bytes, stream);

  int gE = (E + 255) / 256;
  int gN = (N + 255) / 256;
  int gP = (P + 255) / 256;
  deg_kernel<<<gE, 256, 0, stream>>>(dstv, eattr, deg, asum, E);
  scan_kernel<<<1, 1024, 0, stream>>>(deg, row_ptr, N);
  scatter_kernel<<<gE, 256, 0, stream>>>(srcv, dstv, eattr, row_ptr, fill, col_idx, dstpos, evalv, E);
  selfloop_kernel<<<gN, 256, 0, stream>>>(deg, asum, row_ptr, col_idx, dstpos, evalv, N);
  wedot_kernel<<<1, 64, 0, stream>>>(We0, ae0, We1, ae1, We2, ae2, wedot);

  int gGemm = (N + 31) / 32;
  int gNode4 = (N + 3) / 4;

  // ---- layer 0
  gemm_dots_kernel<16, 256, 4><<<gGemm, 256, 0, stream>>>(x, W0, as0, ad0, bufB, al_s, al_d, N);
  ew_kernel<4><<<gP, 256, 0, stream>>>(col_idx, dstpos, evalv, al_s, al_d, wedot, ewb, P);
  agg4_kernel<<<gNode4, 256, 0, stream>>>(row_ptr, col_idx, ewb, bufB, b0, bufA, N);

  // ---- layer 1
  gemm_dots_kernel<256, 256, 4><<<gGemm, 256, 0, stream>>>(bufA, W1, as1, ad1, bufB, al_s, al_d, N);
  ew_kernel<4><<<gP, 256, 0, stream>>>(col_idx, dstpos, evalv, al_s, al_d, wedot + 4, ewb, P);
  agg4_kernel<<<gNode4, 256, 0, stream>>>(row_ptr, col_idx, ewb, bufB, b1, bufA, N);

  // ---- layer 2 (+ LayerNorm -> d_out)
  gemm_dots_kernel<256, 64, 1><<<gGemm, 256, 0, stream>>>(bufA, W2, as2, ad2, bufB, al_s, al_d, N);
  ew_kernel<1><<<gP, 256, 0, stream>>>(col_idx, dstpos, evalv, al_s, al_d, wedot + 8, ewb, P);
  agg_ln_kernel<<<gNode4, 256, 0, stream>>>(row_ptr, col_idx, ewb, bufB, b2, lng, lnb, outp, N);
}

// Round 3
// 389.457 us; speedup vs baseline: 1.3049x; 1.1299x over previous
//
#include <hip/hip_runtime.h>
#include <hip/hip_bf16.h>
#include <math.h>

// GAT x3 + LayerNorm for MI355X (gfx950).
// R3: layer-1/2 GEMMs -> bf16 MFMA 16x16x32 (A = agg output stored bf16,
// B = W pre-reordered into fragment order, L2-resident, no LDS), dots fused.
// Layer-0 GEMM (K=16) stays f32. Aggregation: one wave/node, float4 rows.

typedef __attribute__((ext_vector_type(8))) short short8;
typedef __attribute__((ext_vector_type(4))) float float4v;

__device__ __forceinline__ float wave_sum(float v) {
#pragma unroll
  for (int off = 32; off > 0; off >>= 1) v += __shfl_xor(v, off, 64);
  return v;
}

__device__ __forceinline__ unsigned short f2bf(float v) {
  unsigned u = __float_as_uint(v);
  unsigned r = u + 0x7fff + ((u >> 16) & 1);  // RNE
  return (unsigned short)(r >> 16);
}

__global__ void deg_kernel(const int* __restrict__ dst, const float* __restrict__ eattr,
                           int* __restrict__ deg, float* __restrict__ asum, int E) {
  int e = blockIdx.x * 256 + threadIdx.x;
  if (e >= E) return;
  int d = dst[e];
  atomicAdd(&deg[d], 1);
  atomicAdd(&asum[d], eattr[e]);
}

// row_ptr = exclusive scan of (deg[i]+1); single block, shfl-based.
__global__ __launch_bounds__(1024) void scan_kernel(const int* __restrict__ deg,
                                                    int* __restrict__ row_ptr, int n) {
  __shared__ int wexc[16];
  __shared__ int carry, chunk_tot;
  int tid = threadIdx.x, wid = tid >> 6, lane = tid & 63;
  if (tid == 0) carry = 0;
  __syncthreads();
  for (int base = 0; base < n; base += 1024) {
    int i = base + tid;
    int v = (i < n) ? (deg[i] + 1) : 0;
    int sc = v;
#pragma unroll
    for (int off = 1; off < 64; off <<= 1) {
      int t = __shfl_up(sc, off, 64);
      if (lane >= off) sc += t;
    }
    if (lane == 63) wexc[wid] = sc;
    __syncthreads();
    if (tid == 0) {
      int run = 0;
#pragma unroll
      for (int wI = 0; wI < 16; wI++) { int t = wexc[wI]; wexc[wI] = run; run += t; }
      chunk_tot = run;
    }
    __syncthreads();
    if (i < n) row_ptr[i] = carry + wexc[wid] + sc - v;
    __syncthreads();
    if (tid == 0) carry += chunk_tot;
    __syncthreads();
  }
  if (threadIdx.x == 0) row_ptr[n] = carry;
}

__global__ void scatter_kernel(const int* __restrict__ src, const int* __restrict__ dst,
                               const float* __restrict__ eattr, const int* __restrict__ row_ptr,
                               int* __restrict__ fill, int* __restrict__ col_idx,
                               int* __restrict__ dstpos, float* __restrict__ evalv, int E) {
  int e = blockIdx.x * 256 + threadIdx.x;
  if (e >= E) return;
  int d = dst[e];
  int pos = row_ptr[d] + atomicAdd(&fill[d], 1);
  col_idx[pos] = src[e];
  dstpos[pos] = d;
  evalv[pos] = eattr[e];
}

__global__ void selfloop_kernel(const int* __restrict__ deg, const float* __restrict__ asum,
                                const int* __restrict__ row_ptr, int* __restrict__ col_idx,
                                int* __restrict__ dstpos, float* __restrict__ evalv, int n) {
  int i = blockIdx.x * 256 + threadIdx.x;
  if (i >= n) return;
  int d = deg[i];
  int pos = row_ptr[i] + d;  // self loop last in row
  col_idx[pos] = i;
  dstpos[pos] = i;
  evalv[pos] = asum[i] / fmaxf((float)d, 1.f);
}

__global__ void wedot_kernel(const float* __restrict__ We0, const float* __restrict__ ae0,
                             const float* __restrict__ We1, const float* __restrict__ ae1,
                             const float* __restrict__ We2, const float* __restrict__ ae2,
                             float* __restrict__ wedot) {
  int c = threadIdx.x;
  for (int h = 0; h < 4; h++) {
    float v = wave_sum(We0[h * 64 + c] * ae0[h * 64 + c]);
    if (c == 0) wedot[h] = v;
  }
  for (int h = 0; h < 4; h++) {
    float v = wave_sum(We1[h * 64 + c] * ae1[h * 64 + c]);
    if (c == 0) wedot[4 + h] = v;
  }
  float v = wave_sum(We2[c] * ae2[c]);
  if (c == 0) wedot[8] = v;
}

// Reorder W[K=256, M] f32 -> bf16 fragment order for 16x16x32 MFMA B-operand:
// Wfrag[nt][ks][lane][j] = W[ks*32 + (lane>>4)*8 + j][nt*16 + (lane&15)]
template <int M>
__global__ void wreorder_kernel(const float* __restrict__ W, unsigned short* __restrict__ Wf) {
  int idx = blockIdx.x * 256 + threadIdx.x;
  if (idx >= M * 256) return;
  int j = idx & 7, lane = (idx >> 3) & 63, ks = (idx >> 9) & 7, nt = idx >> 12;
  int k = ks * 32 + (lane >> 4) * 8 + j;
  int ncol = nt * 16 + (lane & 15);
  Wf[idx] = f2bf(W[(size_t)k * M + ncol]);
}

// f32 GEMM for layer 0 (K=16): out[n,M] = in[n,K]@W + fused head dots.
template <int K, int M, int H>
__global__ __launch_bounds__(256) void gemm_dots_kernel(
    const float* __restrict__ in, const float* __restrict__ W,
    const float* __restrict__ a_s, const float* __restrict__ a_d,
    float* __restrict__ out, float* __restrict__ al_s, float* __restrict__ al_d, int n) {
  constexpr int CT = M / 64;
  constexpr int ROWS = 32;
  constexpr int T = 8;
  static_assert(CT == H, "head slice must equal col-tile slot");
  __shared__ float4 lds[ROWS * K / 4];
  int row0 = blockIdx.x * ROWS;
  int tid = threadIdx.x;
  int total4 = ROWS * K / 4;
  const float4* in4 = (const float4*)(in + (size_t)row0 * K);
  if (row0 + ROWS <= n) {
    for (int i = tid; i < total4; i += 256) lds[i] = in4[i];
  } else {
    float4 z = make_float4(0.f, 0.f, 0.f, 0.f);
    for (int i = tid; i < total4; i += 256) {
      int r = row0 + (i * 4) / K;
      lds[i] = (r < n) ? in4[i] : z;
    }
  }
  __syncthreads();
  int c0 = tid & 63;
  int rg = tid >> 6;
  float acc[T][CT];
#pragma unroll
  for (int t = 0; t < T; t++)
#pragma unroll
    for (int c = 0; c < CT; c++) acc[t][c] = 0.f;

  for (int k4 = 0; k4 < K; k4 += 4) {
    float wv[4][CT];
#pragma unroll
    for (int kk = 0; kk < 4; kk++)
#pragma unroll
      for (int c = 0; c < CT; c++) wv[kk][c] = W[(size_t)(k4 + kk) * M + c0 + 64 * c];
#pragma unroll
    for (int t = 0; t < T; t++) {
      float4 xv = lds[(rg * T + t) * (K / 4) + (k4 >> 2)];
      const float* xs = (const float*)&xv;
#pragma unroll
      for (int kk = 0; kk < 4; kk++)
#pragma unroll
        for (int c = 0; c < CT; c++) acc[t][c] = fmaf(xs[kk], wv[kk][c], acc[t][c]);
    }
  }
#pragma unroll
  for (int t = 0; t < T; t++) {
    int r = row0 + rg * T + t;
    if (r < n) {
#pragma unroll
      for (int c = 0; c < CT; c++) out[(size_t)r * M + c0 + 64 * c] = acc[t][c];
#pragma unroll
      for (int h = 0; h < H; h++) {
        float vs = acc[t][h] * a_s[h * 64 + c0];
        float vd = acc[t][h] * a_d[h * 64 + c0];
#pragma unroll
        for (int off = 32; off > 0; off >>= 1) {
          vs += __shfl_xor(vs, off, 64);
          vd += __shfl_xor(vd, off, 64);
        }
        if (c0 == 0) {
          al_s[(size_t)r * H + h] = vs;
          al_d[(size_t)r * H + h] = vd;
        }
      }
    }
  }
}

// bf16 MFMA GEMM (K=256): out[n,M] = A[n,256]@W + fused head dots.
// One wave per 16-row strip; full A-strip in 32 VGPRs; B-frags from global
// (fragment-ordered, coalesced dwordx4, L2-resident). Col-tiles in pairs.
template <int M, int H>
__global__ __launch_bounds__(64) void mfma_gemm_dots(
    const unsigned short* __restrict__ Abf, const unsigned short* __restrict__ Wfrag,
    const float* __restrict__ a_s, const float* __restrict__ a_d,
    float* __restrict__ out, float* __restrict__ al_s, float* __restrict__ al_d, int n) {
  int lane = threadIdx.x;
  int row0 = blockIdx.x * 16;
  int m = lane & 15, q = lane >> 4;

  short8 afrag[8];
  int r = row0 + m;
  if (r < n) {
    const short8* arow = (const short8*)(Abf + (size_t)r * 256);
#pragma unroll
    for (int ks = 0; ks < 8; ks++) afrag[ks] = arow[ks * 4 + q];
  } else {
#pragma unroll
    for (int ks = 0; ks < 8; ks++) afrag[ks] = (short8)0;
  }

  float ps[4] = {0.f, 0.f, 0.f, 0.f}, pd[4] = {0.f, 0.f, 0.f, 0.f};
  const short8* wf = (const short8*)Wfrag;

  auto epi = [&](int tile, float4v acc) {
    int col = tile * 16 + m;
    float asv = a_s[col], adv = a_d[col];
#pragma unroll
    for (int reg = 0; reg < 4; reg++) {
      int rr = row0 + q * 4 + reg;
      if (rr < n) out[(size_t)rr * M + col] = acc[reg];
      ps[reg] = fmaf(acc[reg], asv, ps[reg]);
      pd[reg] = fmaf(acc[reg], adv, pd[reg]);
    }
    if ((tile & 3) == 3) {
      int h = tile >> 2;
#pragma unroll
      for (int reg = 0; reg < 4; reg++) {
        float vs = ps[reg], vd = pd[reg];
#pragma unroll
        for (int off = 1; off < 16; off <<= 1) {
          vs += __shfl_xor(vs, off, 64);
          vd += __shfl_xor(vd, off, 64);
        }
        if (m == 0) {
          int rr = row0 + q * 4 + reg;
          if (rr < n) {
            al_s[(size_t)rr * H + h] = vs;
            al_d[(size_t)rr * H + h] = vd;
          }
        }
        ps[reg] = 0.f;
        pd[reg] = 0.f;
      }
    }
  };

  for (int nt = 0; nt < M / 16; nt += 2) {
    const short8* b0 = wf + (size_t)nt * 8 * 64 + lane;
    const short8* b1 = b0 + 8 * 64;
    short8 bf0[8], bf1[8];
#pragma unroll
    for (int ks = 0; ks < 8; ks++) {
      bf0[ks] = b0[ks * 64];
      bf1[ks] = b1[ks * 64];
    }
    float4v acc0 = {0.f, 0.f, 0.f, 0.f};
    float4v acc1 = {0.f, 0.f, 0.f, 0.f};
#pragma unroll
    for (int ks = 0; ks < 8; ks++) {
      acc0 = __builtin_amdgcn_mfma_f32_16x16x32_bf16(afrag[ks], bf0[ks], acc0, 0, 0, 0);
      acc1 = __builtin_amdgcn_mfma_f32_16x16x32_bf16(afrag[ks], bf1[ks], acc1, 0, 0, 0);
    }
    epi(nt, acc0);
    epi(nt + 1, acc1);
  }
}

// Edge-parallel softmax weights (max cancels in the ratio; exps clamped).
template <int H>
__global__ void ew_kernel(const int* __restrict__ col_idx, const int* __restrict__ dstpos,
                          const float* __restrict__ evalv, const float* __restrict__ al_s,
                          const float* __restrict__ al_d, const float* __restrict__ wedot,
                          float* __restrict__ ew, int P) {
  int p = blockIdx.x * 256 + threadIdx.x;
  if (p >= P) return;
  int s = col_idx[p];
  int d = dstpos[p];
  float ev = evalv[p];
#pragma unroll
  for (int h = 0; h < H; h++) {
    float a = al_s[(size_t)s * H + h] + al_d[(size_t)d * H + h] + ev * wedot[h];
    a = fmaxf(a, 0.2f * a);
    a = fminf(a, 30.f);
    ew[(size_t)p * H + h] = __expf(a);
  }
}

// H=4 aggregation: one wave/node, lane c holds channels 4c..4c+3 (head=c>>4).
// bias+ELU fused; writes bf16 (feeds next MFMA GEMM).
__global__ __launch_bounds__(256) void agg4_kernel(
    const int* __restrict__ row_ptr, const int* __restrict__ col_idx,
    const float* __restrict__ ew, const float* __restrict__ B,
    const float* __restrict__ bias, unsigned short* __restrict__ out, int n) {
  int node = blockIdx.x * 4 + (threadIdx.x >> 6);
  int c = threadIdx.x & 63;
  if (node >= n) return;
  int h4 = c >> 4;
  int beg = row_ptr[node], end = row_ptr[node + 1];
  const float4* Bp = (const float4*)B;
  float4 acc = make_float4(0.f, 0.f, 0.f, 0.f);
  float den = 0.f;
  int s = col_idx[beg];
  float w = ew[(size_t)beg * 4 + h4];
  float4 bv = Bp[(size_t)s * 64 + c];
  for (int e = beg + 1; e < end; e++) {
    int s2 = col_idx[e];
    float w2 = ew[(size_t)e * 4 + h4];
    float4 bv2 = Bp[(size_t)s2 * 64 + c];
    den += w;
    acc.x = fmaf(w, bv.x, acc.x);
    acc.y = fmaf(w, bv.y, acc.y);
    acc.z = fmaf(w, bv.z, acc.z);
    acc.w = fmaf(w, bv.w, acc.w);
    w = w2;
    bv = bv2;
  }
  den += w;
  acc.x = fmaf(w, bv.x, acc.x);
  acc.y = fmaf(w, bv.y, acc.y);
  acc.z = fmaf(w, bv.z, acc.z);
  acc.w = fmaf(w, bv.w, acc.w);
  float inv = 1.f / (den + 1e-16f);
  float4 b4 = ((const float4*)bias)[c];
  float ox = acc.x * inv + b4.x;
  float oy = acc.y * inv + b4.y;
  float oz = acc.z * inv + b4.z;
  float ow = acc.w * inv + b4.w;
  ox = ox > 0.f ? ox : expm1f(ox);
  oy = oy > 0.f ? oy : expm1f(oy);
  oz = oz > 0.f ? oz : expm1f(oz);
  ow = ow > 0.f ? ow : expm1f(ow);
  ushort4 o4;
  o4.x = f2bf(ox);
  o4.y = f2bf(oy);
  o4.z = f2bf(oz);
  o4.w = f2bf(ow);
  ((ushort4*)out)[(size_t)node * 64 + c] = o4;
}

// H=1 aggregation + bias + LayerNorm fused; one wave per node.
__global__ __launch_bounds__(256) void agg_ln_kernel(
    const int* __restrict__ row_ptr, const int* __restrict__ col_idx,
    const float* __restrict__ ew, const float* __restrict__ B,
    const float* __restrict__ bias, const float* __restrict__ ln_g,
    const float* __restrict__ ln_b, float* __restrict__ out, int n) {
  int node = blockIdx.x * 4 + (threadIdx.x >> 6);
  int c = threadIdx.x & 63;
  if (node >= n) return;
  int beg = row_ptr[node], end = row_ptr[node + 1];
  float acc = 0.f, den = 0.f;
  int s = col_idx[beg];
  float w = ew[beg];
  float bv = B[(size_t)s * 64 + c];
  for (int e = beg + 1; e < end; e++) {
    int s2 = col_idx[e];
    float w2 = ew[e];
    float bv2 = B[(size_t)s2 * 64 + c];
    den += w;
    acc = fmaf(w, bv, acc);
    w = w2;
    bv = bv2;
  }
  den += w;
  acc = fmaf(w, bv, acc);
  float o = acc / (den + 1e-16f) + bias[c];
  float mu = wave_sum(o) * (1.f / 64.f);
  float dv = o - mu;
  float var = wave_sum(dv * dv) * (1.f / 64.f);
  out[(size_t)node * 64 + c] = dv * rsqrtf(var + 1e-5f) * ln_g[c] + ln_b[c];
}

extern "C" void kernel_launch(void* const* d_in, const int* in_sizes, int n_in,
                              void* d_out, int out_size, void* d_ws, size_t ws_size,
                              hipStream_t stream) {
  const float* x = (const float*)d_in[0];
  const int* ei = (const int*)d_in[1];
  const float* eattr = (const float*)d_in[2];
  const float* W0 = (const float*)d_in[3];
  const float* as0 = (const float*)d_in[4];
  const float* ad0 = (const float*)d_in[5];
  const float* We0 = (const float*)d_in[6];
  const float* ae0 = (const float*)d_in[7];
  const float* b0 = (const float*)d_in[8];
  const float* W1 = (const float*)d_in[9];
  const float* as1 = (const float*)d_in[10];
  const float* ad1 = (const float*)d_in[11];
  const float* We1 = (const float*)d_in[12];
  const float* ae1 = (const float*)d_in[13];
  const float* b1 = (const float*)d_in[14];
  const float* W2 = (const float*)d_in[15];
  const float* as2 = (const float*)d_in[16];
  const float* ad2 = (const float*)d_in[17];
  const float* We2 = (const float*)d_in[18];
  const float* ae2 = (const float*)d_in[19];
  const float* b2 = (const float*)d_in[20];
  const float* lng = (const float*)d_in[21];
  const float* lnb = (const float*)d_in[22];
  float* outp = (float*)d_out;

  const int N = in_sizes[0] / 16;
  const int E = in_sizes[1] / 2;
  const int P = E + N;
  const int* srcv = ei;
  const int* dstv = ei + E;

  char* w = (char*)d_ws;
  size_t off = 0;
  auto alloc = [&](size_t bytes) -> void* {
    void* p = w + off;
    off += (bytes + 255) & ~(size_t)255;
    return p;
  };
  int* deg = (int*)alloc((size_t)N * 4);
  float* asum = (float*)alloc((size_t)N * 4);
  int* fill = (int*)alloc((size_t)N * 4);
  size_t zero_bytes = off;
  int* row_ptr = (int*)alloc((size_t)(N + 1) * 4);
  int* col_idx = (int*)alloc((size_t)P * 4);
  int* dstpos = (int*)alloc((size_t)P * 4);
  float* evalv = (float*)alloc((size_t)P * 4);
  float* wedot = (float*)alloc(16 * 4);
  float* al_s = (float*)alloc((size_t)N * 4 * 4);
  float* al_d = (float*)alloc((size_t)N * 4 * 4);
  float* ewb = (float*)alloc((size_t)P * 4 * 4);
  unsigned short* Wf1 = (unsigned short*)alloc(256 * 256 * 2);
  unsigned short* Wf2 = (unsigned short*)alloc(256 * 64 * 2);
  unsigned short* bufA = (unsigned short*)alloc((size_t)N * 256 * 2);  // bf16
  float* bufB = (float*)alloc((size_t)N * 256 * 4);                    // f32
  (void)ws_size;

  hipMemsetAsync(d_ws, 0, zero_bytes, stream);

  int gE = (E + 255) / 256;
  int gN = (N + 255) / 256;
  int gP = (P + 255) / 256;
  deg_kernel<<<gE, 256, 0, stream>>>(dstv, eattr, deg, asum, E);
  scan_kernel<<<1, 1024, 0, stream>>>(deg, row_ptr, N);
  scatter_kernel<<<gE, 256, 0, stream>>>(srcv, dstv, eattr, row_ptr, fill, col_idx, dstpos, evalv, E);
  selfloop_kernel<<<gN, 256, 0, stream>>>(deg, asum, row_ptr, col_idx, dstpos, evalv, N);
  wedot_kernel<<<1, 64, 0, stream>>>(We0, ae0, We1, ae1, We2, ae2, wedot);
  wreorder_kernel<256><<<256, 256, 0, stream>>>(W1, Wf1);
  wreorder_kernel<64><<<64, 256, 0, stream>>>(W2, Wf2);

  int gGemm0 = (N + 31) / 32;
  int gStrip = (N + 15) / 16;
  int gNode4 = (N + 3) / 4;

  // ---- layer 0 (f32 GEMM, K=16)
  gemm_dots_kernel<16, 256, 4><<<gGemm0, 256, 0, stream>>>(x, W0, as0, ad0, bufB, al_s, al_d, N);
  ew_kernel<4><<<gP, 256, 0, stream>>>(col_idx, dstpos, evalv, al_s, al_d, wedot, ewb, P);
  agg4_kernel<<<gNode4, 256, 0, stream>>>(row_ptr, col_idx, ewb, bufB, b0, bufA, N);

  // ---- layer 1 (bf16 MFMA GEMM)
  mfma_gemm_dots<256, 4><<<gStrip, 64, 0, stream>>>(bufA, Wf1, as1, ad1, bufB, al_s, al_d, N);
  ew_kernel<4><<<gP, 256, 0, stream>>>(col_idx, dstpos, evalv, al_s, al_d, wedot + 4, ewb, P);
  agg4_kernel<<<gNode4, 256, 0, stream>>>(row_ptr, col_idx, ewb, bufB, b1, bufA, N);

  // ---- layer 2 (bf16 MFMA GEMM, M=64) + LayerNorm -> d_out
  mfma_gemm_dots<64, 1><<<gStrip, 64, 0, stream>>>(bufA, Wf2, as2, ad2, bufB, al_s, al_d, N);
  ew_kernel<1><<<gP, 256, 0, stream>>>(col_idx, dstpos, evalv, al_s, al_d, wedot + 8, ewb, P);
  agg_ln_kernel<<<gNode4, 256, 0, stream>>>(row_ptr, col_idx, ewb, bufB, b2, lng, lnb, outp, N);
}

// Round 4
// 374.974 us; speedup vs baseline: 1.3553x; 1.0386x over previous
//
#include <hip/hip_runtime.h>
#include <hip/hip_bf16.h>
#include <math.h>

// GAT x3 + LayerNorm for MI355X (gfx950).
// R4: h carried bf16 end-to-end (halves gather bytes in aggregation, the
// miss-BW-bound hot spot); exp-weights computed inline in aggregation
// (each edge weight has exactly one consumer); edge record packed int2.
// GEMMs: layer0 f32-compute/bf16-store; layers 1-2 bf16 MFMA 16x16x32 with
// W pre-reordered to fragment order (L2-resident, no LDS); attention dots
// fused into all GEMM epilogues.

typedef __attribute__((ext_vector_type(8))) short short8;
typedef __attribute__((ext_vector_type(4))) float float4v;

__device__ __forceinline__ float wave_sum(float v) {
#pragma unroll
  for (int off = 32; off > 0; off >>= 1) v += __shfl_xor(v, off, 64);
  return v;
}

__device__ __forceinline__ unsigned short f2bf(float v) {
  unsigned u = __float_as_uint(v);
  unsigned r = u + 0x7fff + ((u >> 16) & 1);  // RNE
  return (unsigned short)(r >> 16);
}

__device__ __forceinline__ float bf2f(unsigned short u) {
  return __uint_as_float(((unsigned)u) << 16);
}

__global__ void deg_kernel(const int* __restrict__ dst, const float* __restrict__ eattr,
                           int* __restrict__ deg, float* __restrict__ asum, int E) {
  int e = blockIdx.x * 256 + threadIdx.x;
  if (e >= E) return;
  int d = dst[e];
  atomicAdd(&deg[d], 1);
  atomicAdd(&asum[d], eattr[e]);
}

// row_ptr = exclusive scan of (deg[i]+1); single block, shfl-based.
__global__ __launch_bounds__(1024) void scan_kernel(const int* __restrict__ deg,
                                                    int* __restrict__ row_ptr, int n) {
  __shared__ int wexc[16];
  __shared__ int carry, chunk_tot;
  int tid = threadIdx.x, wid = tid >> 6, lane = tid & 63;
  if (tid == 0) carry = 0;
  __syncthreads();
  for (int base = 0; base < n; base += 1024) {
    int i = base + tid;
    int v = (i < n) ? (deg[i] + 1) : 0;
    int sc = v;
#pragma unroll
    for (int off = 1; off < 64; off <<= 1) {
      int t = __shfl_up(sc, off, 64);
      if (lane >= off) sc += t;
    }
    if (lane == 63) wexc[wid] = sc;
    __syncthreads();
    if (tid == 0) {
      int run = 0;
#pragma unroll
      for (int wI = 0; wI < 16; wI++) { int t = wexc[wI]; wexc[wI] = run; run += t; }
      chunk_tot = run;
    }
    __syncthreads();
    if (i < n) row_ptr[i] = carry + wexc[wid] + sc - v;
    __syncthreads();
    if (tid == 0) carry += chunk_tot;
    __syncthreads();
  }
  if (threadIdx.x == 0) row_ptr[n] = carry;
}

// edge[pos] = {src, bitcast(eattr)} in dst-CSR order.
__global__ void scatter_kernel(const int* __restrict__ src, const int* __restrict__ dst,
                               const float* __restrict__ eattr, const int* __restrict__ row_ptr,
                               int* __restrict__ fill, int2* __restrict__ edge, int E) {
  int e = blockIdx.x * 256 + threadIdx.x;
  if (e >= E) return;
  int d = dst[e];
  int pos = row_ptr[d] + atomicAdd(&fill[d], 1);
  edge[pos] = make_int2(src[e], __float_as_int(eattr[e]));
}

__global__ void selfloop_kernel(const int* __restrict__ deg, const float* __restrict__ asum,
                                const int* __restrict__ row_ptr, int2* __restrict__ edge, int n) {
  int i = blockIdx.x * 256 + threadIdx.x;
  if (i >= n) return;
  int d = deg[i];
  int pos = row_ptr[i] + d;  // self loop last in row
  edge[pos] = make_int2(i, __float_as_int(asum[i] / fmaxf((float)d, 1.f)));
}

// wedot[0..3]=layer0 heads, [4..7]=layer1 heads, [8]=layer2
__global__ void wedot_kernel(const float* __restrict__ We0, const float* __restrict__ ae0,
                             const float* __restrict__ We1, const float* __restrict__ ae1,
                             const float* __restrict__ We2, const float* __restrict__ ae2,
                             float* __restrict__ wedot) {
  int c = threadIdx.x;
  for (int h = 0; h < 4; h++) {
    float v = wave_sum(We0[h * 64 + c] * ae0[h * 64 + c]);
    if (c == 0) wedot[h] = v;
  }
  for (int h = 0; h < 4; h++) {
    float v = wave_sum(We1[h * 64 + c] * ae1[h * 64 + c]);
    if (c == 0) wedot[4 + h] = v;
  }
  float v = wave_sum(We2[c] * ae2[c]);
  if (c == 0) wedot[8] = v;
}

// Reorder W[K=256, M] f32 -> bf16 fragment order for 16x16x32 MFMA B-operand.
template <int M>
__global__ void wreorder_kernel(const float* __restrict__ W, unsigned short* __restrict__ Wf) {
  int idx = blockIdx.x * 256 + threadIdx.x;
  if (idx >= M * 256) return;
  int j = idx & 7, lane = (idx >> 3) & 63, ks = (idx >> 9) & 7, nt = idx >> 12;
  int k = ks * 32 + (lane >> 4) * 8 + j;
  int ncol = nt * 16 + (lane & 15);
  Wf[idx] = f2bf(W[(size_t)k * M + ncol]);
}

// f32 GEMM for layer 0 (K=16): bf16 out + fused head dots.
template <int K, int M, int H>
__global__ __launch_bounds__(256) void gemm_dots_kernel(
    const float* __restrict__ in, const float* __restrict__ W,
    const float* __restrict__ a_s, const float* __restrict__ a_d,
    unsigned short* __restrict__ out, float* __restrict__ al_s, float* __restrict__ al_d,
    int n) {
  constexpr int CT = M / 64;
  constexpr int ROWS = 32;
  constexpr int T = 8;
  static_assert(CT == H, "head slice must equal col-tile slot");
  __shared__ float4 lds[ROWS * K / 4];
  int row0 = blockIdx.x * ROWS;
  int tid = threadIdx.x;
  int total4 = ROWS * K / 4;
  const float4* in4 = (const float4*)(in + (size_t)row0 * K);
  if (row0 + ROWS <= n) {
    for (int i = tid; i < total4; i += 256) lds[i] = in4[i];
  } else {
    float4 z = make_float4(0.f, 0.f, 0.f, 0.f);
    for (int i = tid; i < total4; i += 256) {
      int r = row0 + (i * 4) / K;
      lds[i] = (r < n) ? in4[i] : z;
    }
  }
  __syncthreads();
  int c0 = tid & 63;
  int rg = tid >> 6;
  float acc[T][CT];
#pragma unroll
  for (int t = 0; t < T; t++)
#pragma unroll
    for (int c = 0; c < CT; c++) acc[t][c] = 0.f;

  for (int k4 = 0; k4 < K; k4 += 4) {
    float wv[4][CT];
#pragma unroll
    for (int kk = 0; kk < 4; kk++)
#pragma unroll
      for (int c = 0; c < CT; c++) wv[kk][c] = W[(size_t)(k4 + kk) * M + c0 + 64 * c];
#pragma unroll
    for (int t = 0; t < T; t++) {
      float4 xv = lds[(rg * T + t) * (K / 4) + (k4 >> 2)];
      const float* xs = (const float*)&xv;
#pragma unroll
      for (int kk = 0; kk < 4; kk++)
#pragma unroll
        for (int c = 0; c < CT; c++) acc[t][c] = fmaf(xs[kk], wv[kk][c], acc[t][c]);
    }
  }
#pragma unroll
  for (int t = 0; t < T; t++) {
    int r = row0 + rg * T + t;
    if (r < n) {
#pragma unroll
      for (int c = 0; c < CT; c++) out[(size_t)r * M + c0 + 64 * c] = f2bf(acc[t][c]);
#pragma unroll
      for (int h = 0; h < H; h++) {
        float vs = acc[t][h] * a_s[h * 64 + c0];
        float vd = acc[t][h] * a_d[h * 64 + c0];
#pragma unroll
        for (int off = 32; off > 0; off >>= 1) {
          vs += __shfl_xor(vs, off, 64);
          vd += __shfl_xor(vd, off, 64);
        }
        if (c0 == 0) {
          al_s[(size_t)r * H + h] = vs;
          al_d[(size_t)r * H + h] = vd;
        }
      }
    }
  }
}

// bf16 MFMA GEMM (K=256): bf16 out + fused head dots. One wave / 16-row strip.
template <int M, int H>
__global__ __launch_bounds__(64) void mfma_gemm_dots(
    const unsigned short* __restrict__ Abf, const unsigned short* __restrict__ Wfrag,
    const float* __restrict__ a_s, const float* __restrict__ a_d,
    unsigned short* __restrict__ out, float* __restrict__ al_s, float* __restrict__ al_d,
    int n) {
  int lane = threadIdx.x;
  int row0 = blockIdx.x * 16;
  int m = lane & 15, q = lane >> 4;

  short8 afrag[8];
  int r = row0 + m;
  if (r < n) {
    const short8* arow = (const short8*)(Abf + (size_t)r * 256);
#pragma unroll
    for (int ks = 0; ks < 8; ks++) afrag[ks] = arow[ks * 4 + q];
  } else {
#pragma unroll
    for (int ks = 0; ks < 8; ks++) afrag[ks] = (short8)0;
  }

  float ps[4] = {0.f, 0.f, 0.f, 0.f}, pd[4] = {0.f, 0.f, 0.f, 0.f};
  const short8* wf = (const short8*)Wfrag;

  auto epi = [&](int tile, float4v acc) {
    int col = tile * 16 + m;
    float asv = a_s[col], adv = a_d[col];
#pragma unroll
    for (int reg = 0; reg < 4; reg++) {
      int rr = row0 + q * 4 + reg;
      if (rr < n) out[(size_t)rr * M + col] = f2bf(acc[reg]);
      ps[reg] = fmaf(acc[reg], asv, ps[reg]);
      pd[reg] = fmaf(acc[reg], adv, pd[reg]);
    }
    if ((tile & 3) == 3) {
      int h = tile >> 2;
#pragma unroll
      for (int reg = 0; reg < 4; reg++) {
        float vs = ps[reg], vd = pd[reg];
#pragma unroll
        for (int off = 1; off < 16; off <<= 1) {
          vs += __shfl_xor(vs, off, 64);
          vd += __shfl_xor(vd, off, 64);
        }
        if (m == 0) {
          int rr = row0 + q * 4 + reg;
          if (rr < n) {
            al_s[(size_t)rr * H + h] = vs;
            al_d[(size_t)rr * H + h] = vd;
          }
        }
        ps[reg] = 0.f;
        pd[reg] = 0.f;
      }
    }
  };

  for (int nt = 0; nt < M / 16; nt += 2) {
    const short8* b0 = wf + (size_t)nt * 8 * 64 + lane;
    const short8* b1 = b0 + 8 * 64;
    short8 bf0[8], bf1[8];
#pragma unroll
    for (int ks = 0; ks < 8; ks++) {
      bf0[ks] = b0[ks * 64];
      bf1[ks] = b1[ks * 64];
    }
    float4v acc0 = {0.f, 0.f, 0.f, 0.f};
    float4v acc1 = {0.f, 0.f, 0.f, 0.f};
#pragma unroll
    for (int ks = 0; ks < 8; ks++) {
      acc0 = __builtin_amdgcn_mfma_f32_16x16x32_bf16(afrag[ks], bf0[ks], acc0, 0, 0, 0);
      acc1 = __builtin_amdgcn_mfma_f32_16x16x32_bf16(afrag[ks], bf1[ks], acc1, 0, 0, 0);
    }
    epi(nt, acc0);
    epi(nt + 1, acc1);
  }
}

// H=4 aggregation, exp weights inline (softmax max cancels; clamp 30).
// One wave/node; lane c holds channels 4c..4c+3, head = c>>4. B is bf16.
// bias+ELU fused; writes bf16 (feeds next MFMA GEMM).
__global__ __launch_bounds__(256) void agg4_kernel(
    const int* __restrict__ row_ptr, const int2* __restrict__ edge,
    const float* __restrict__ al_s, const float* __restrict__ al_d,
    const float* __restrict__ wedot, const unsigned short* __restrict__ B,
    const float* __restrict__ bias, unsigned short* __restrict__ out, int n) {
  int node = blockIdx.x * 4 + (threadIdx.x >> 6);
  int c = threadIdx.x & 63;
  if (node >= n) return;
  int h4 = c >> 4;
  float wd = wedot[h4];
  float adn = al_d[(size_t)node * 4 + h4];
  int beg = row_ptr[node], end = row_ptr[node + 1];
  const ushort4* Bp = (const ushort4*)B;
  float4 acc = make_float4(0.f, 0.f, 0.f, 0.f);
  float den = 0.f;
  int2 eg = edge[beg];
  float als = al_s[(size_t)eg.x * 4 + h4];
  ushort4 bv = Bp[(size_t)eg.x * 64 + c];
  for (int e = beg + 1; e < end; e++) {
    int2 eg2 = edge[e];
    float als2 = al_s[(size_t)eg2.x * 4 + h4];
    ushort4 bv2 = Bp[(size_t)eg2.x * 64 + c];
    float a = als + adn + __int_as_float(eg.y) * wd;
    a = fmaxf(a, 0.2f * a);
    a = fminf(a, 30.f);
    float w = __expf(a);
    den += w;
    acc.x = fmaf(w, bf2f(bv.x), acc.x);
    acc.y = fmaf(w, bf2f(bv.y), acc.y);
    acc.z = fmaf(w, bf2f(bv.z), acc.z);
    acc.w = fmaf(w, bf2f(bv.w), acc.w);
    eg = eg2;
    als = als2;
    bv = bv2;
  }
  {
    float a = als + adn + __int_as_float(eg.y) * wd;
    a = fmaxf(a, 0.2f * a);
    a = fminf(a, 30.f);
    float w = __expf(a);
    den += w;
    acc.x = fmaf(w, bf2f(bv.x), acc.x);
    acc.y = fmaf(w, bf2f(bv.y), acc.y);
    acc.z = fmaf(w, bf2f(bv.z), acc.z);
    acc.w = fmaf(w, bf2f(bv.w), acc.w);
  }
  float inv = 1.f / (den + 1e-16f);
  float4 b4 = ((const float4*)bias)[c];
  float ox = acc.x * inv + b4.x;
  float oy = acc.y * inv + b4.y;
  float oz = acc.z * inv + b4.z;
  float ow = acc.w * inv + b4.w;
  ox = ox > 0.f ? ox : expm1f(ox);
  oy = oy > 0.f ? oy : expm1f(oy);
  oz = oz > 0.f ? oz : expm1f(oz);
  ow = ow > 0.f ? ow : expm1f(ow);
  ushort4 o4;
  o4.x = f2bf(ox);
  o4.y = f2bf(oy);
  o4.z = f2bf(oz);
  o4.w = f2bf(ow);
  ((ushort4*)out)[(size_t)node * 64 + c] = o4;
}

// H=1 aggregation (exp inline) + bias + LayerNorm fused; one wave per node.
__global__ __launch_bounds__(256) void agg_ln_kernel(
    const int* __restrict__ row_ptr, const int2* __restrict__ edge,
    const float* __restrict__ al_s, const float* __restrict__ al_d,
    const float* __restrict__ wedot, const unsigned short* __restrict__ B,
    const float* __restrict__ bias, const float* __restrict__ ln_g,
    const float* __restrict__ ln_b, float* __restrict__ out, int n) {
  int node = blockIdx.x * 4 + (threadIdx.x >> 6);
  int c = threadIdx.x & 63;
  if (node >= n) return;
  float wd = wedot[0];
  float adn = al_d[node];
  int beg = row_ptr[node], end = row_ptr[node + 1];
  float acc = 0.f, den = 0.f;
  int2 eg = edge[beg];
  float als = al_s[eg.x];
  unsigned short bv = B[(size_t)eg.x * 64 + c];
  for (int e = beg + 1; e < end; e++) {
    int2 eg2 = edge[e];
    float als2 = al_s[eg2.x];
    unsigned short bv2 = B[(size_t)eg2.x * 64 + c];
    float a = als + adn + __int_as_float(eg.y) * wd;
    a = fmaxf(a, 0.2f * a);
    a = fminf(a, 30.f);
    float w = __expf(a);
    den += w;
    acc = fmaf(w, bf2f(bv), acc);
    eg = eg2;
    als = als2;
    bv = bv2;
  }
  {
    float a = als + adn + __int_as_float(eg.y) * wd;
    a = fmaxf(a, 0.2f * a);
    a = fminf(a, 30.f);
    float w = __expf(a);
    den += w;
    acc = fmaf(w, bf2f(bv), acc);
  }
  float o = acc / (den + 1e-16f) + bias[c];
  float mu = wave_sum(o) * (1.f / 64.f);
  float dv = o - mu;
  float var = wave_sum(dv * dv) * (1.f / 64.f);
  out[(size_t)node * 64 + c] = dv * rsqrtf(var + 1e-5f) * ln_g[c] + ln_b[c];
}

extern "C" void kernel_launch(void* const* d_in, const int* in_sizes, int n_in,
                              void* d_out, int out_size, void* d_ws, size_t ws_size,
                              hipStream_t stream) {
  const float* x = (const float*)d_in[0];
  const int* ei = (const int*)d_in[1];
  const float* eattr = (const float*)d_in[2];
  const float* W0 = (const float*)d_in[3];
  const float* as0 = (const float*)d_in[4];
  const float* ad0 = (const float*)d_in[5];
  const float* We0 = (const float*)d_in[6];
  const float* ae0 = (const float*)d_in[7];
  const float* b0 = (const float*)d_in[8];
  const float* W1 = (const float*)d_in[9];
  const float* as1 = (const float*)d_in[10];
  const float* ad1 = (const float*)d_in[11];
  const float* We1 = (const float*)d_in[12];
  const float* ae1 = (const float*)d_in[13];
  const float* b1 = (const float*)d_in[14];
  const float* W2 = (const float*)d_in[15];
  const float* as2 = (const float*)d_in[16];
  const float* ad2 = (const float*)d_in[17];
  const float* We2 = (const float*)d_in[18];
  const float* ae2 = (const float*)d_in[19];
  const float* b2 = (const float*)d_in[20];
  const float* lng = (const float*)d_in[21];
  const float* lnb = (const float*)d_in[22];
  float* outp = (float*)d_out;

  const int N = in_sizes[0] / 16;
  const int E = in_sizes[1] / 2;
  const int P = E + N;
  const int* srcv = ei;
  const int* dstv = ei + E;

  char* w = (char*)d_ws;
  size_t off = 0;
  auto alloc = [&](size_t bytes) -> void* {
    void* p = w + off;
    off += (bytes + 255) & ~(size_t)255;
    return p;
  };
  int* deg = (int*)alloc((size_t)N * 4);
  float* asum = (float*)alloc((size_t)N * 4);
  int* fill = (int*)alloc((size_t)N * 4);
  size_t zero_bytes = off;
  int* row_ptr = (int*)alloc((size_t)(N + 1) * 4);
  int2* edge = (int2*)alloc((size_t)P * 8);
  float* wedot = (float*)alloc(16 * 4);
  float* al_s = (float*)alloc((size_t)N * 4 * 4);
  float* al_d = (float*)alloc((size_t)N * 4 * 4);
  unsigned short* Wf1 = (unsigned short*)alloc(256 * 256 * 2);
  unsigned short* Wf2 = (unsigned short*)alloc(256 * 64 * 2);
  unsigned short* bufA = (unsigned short*)alloc((size_t)N * 256 * 2);  // agg out
  unsigned short* bufB = (unsigned short*)alloc((size_t)N * 256 * 2);  // gemm out
  (void)ws_size;

  hipMemsetAsync(d_ws, 0, zero_bytes, stream);

  int gE = (E + 255) / 256;
  int gN = (N + 255) / 256;
  deg_kernel<<<gE, 256, 0, stream>>>(dstv, eattr, deg, asum, E);
  scan_kernel<<<1, 1024, 0, stream>>>(deg, row_ptr, N);
  scatter_kernel<<<gE, 256, 0, stream>>>(srcv, dstv, eattr, row_ptr, fill, edge, E);
  selfloop_kernel<<<gN, 256, 0, stream>>>(deg, asum, row_ptr, edge, N);
  wedot_kernel<<<1, 64, 0, stream>>>(We0, ae0, We1, ae1, We2, ae2, wedot);
  wreorder_kernel<256><<<256, 256, 0, stream>>>(W1, Wf1);
  wreorder_kernel<64><<<64, 256, 0, stream>>>(W2, Wf2);

  int gGemm0 = (N + 31) / 32;
  int gStrip = (N + 15) / 16;
  int gNode4 = (N + 3) / 4;

  // ---- layer 0
  gemm_dots_kernel<16, 256, 4><<<gGemm0, 256, 0, stream>>>(x, W0, as0, ad0, bufB, al_s, al_d, N);
  agg4_kernel<<<gNode4, 256, 0, stream>>>(row_ptr, edge, al_s, al_d, wedot, bufB, b0, bufA, N);

  // ---- layer 1
  mfma_gemm_dots<256, 4><<<gStrip, 64, 0, stream>>>(bufA, Wf1, as1, ad1, bufB, al_s, al_d, N);
  agg4_kernel<<<gNode4, 256, 0, stream>>>(row_ptr, edge, al_s, al_d, wedot + 4, bufB, b1, bufA, N);

  // ---- layer 2 (+ LayerNorm -> d_out)
  mfma_gemm_dots<64, 1><<<gStrip, 64, 0, stream>>>(bufA, Wf2, as2, ad2, bufB, al_s, al_d, N);
  agg_ln_kernel<<<gNode4, 256, 0, stream>>>(row_ptr, edge, al_s, al_d, wedot + 8, bufB, b2,
                                            lng, lnb, outp, N);
}

// Round 5
// 318.045 us; speedup vs baseline: 1.5979x; 1.1790x over previous
//
#include <hip/hip_runtime.h>
#include <hip/hip_bf16.h>
#include <math.h>

// GAT x3 + LayerNorm for MI355X (gfx950).
// R5: aggregation edge loop chunked x4 (H=4) / x8 (H=1) -> 4-8 independent
// row gathers in flight per wave (was depth-1). R4 carried: bf16 h end-to-end,
// exp weights inline, int2 edge records, MFMA GEMMs with fragment-ordered W.

typedef __attribute__((ext_vector_type(8))) short short8;
typedef __attribute__((ext_vector_type(4))) float float4v;

__device__ __forceinline__ float wave_sum(float v) {
#pragma unroll
  for (int off = 32; off > 0; off >>= 1) v += __shfl_xor(v, off, 64);
  return v;
}

__device__ __forceinline__ unsigned short f2bf(float v) {
  unsigned u = __float_as_uint(v);
  unsigned r = u + 0x7fff + ((u >> 16) & 1);  // RNE
  return (unsigned short)(r >> 16);
}

__device__ __forceinline__ float bf2f(unsigned short u) {
  return __uint_as_float(((unsigned)u) << 16);
}

// leaky_relu(0.2) + clamp + exp (softmax max cancels in the ratio)
__device__ __forceinline__ float edge_w(float a) {
  a = fmaxf(a, 0.2f * a);
  a = fminf(a, 30.f);
  return __expf(a);
}

__global__ void deg_kernel(const int* __restrict__ dst, const float* __restrict__ eattr,
                           int* __restrict__ deg, float* __restrict__ asum, int E) {
  int e = blockIdx.x * 256 + threadIdx.x;
  if (e >= E) return;
  int d = dst[e];
  atomicAdd(&deg[d], 1);
  atomicAdd(&asum[d], eattr[e]);
}

// row_ptr = exclusive scan of (deg[i]+1); single block, shfl-based.
__global__ __launch_bounds__(1024) void scan_kernel(const int* __restrict__ deg,
                                                    int* __restrict__ row_ptr, int n) {
  __shared__ int wexc[16];
  __shared__ int carry, chunk_tot;
  int tid = threadIdx.x, wid = tid >> 6, lane = tid & 63;
  if (tid == 0) carry = 0;
  __syncthreads();
  for (int base = 0; base < n; base += 1024) {
    int i = base + tid;
    int v = (i < n) ? (deg[i] + 1) : 0;
    int sc = v;
#pragma unroll
    for (int off = 1; off < 64; off <<= 1) {
      int t = __shfl_up(sc, off, 64);
      if (lane >= off) sc += t;
    }
    if (lane == 63) wexc[wid] = sc;
    __syncthreads();
    if (tid == 0) {
      int run = 0;
#pragma unroll
      for (int wI = 0; wI < 16; wI++) { int t = wexc[wI]; wexc[wI] = run; run += t; }
      chunk_tot = run;
    }
    __syncthreads();
    if (i < n) row_ptr[i] = carry + wexc[wid] + sc - v;
    __syncthreads();
    if (tid == 0) carry += chunk_tot;
    __syncthreads();
  }
  if (threadIdx.x == 0) row_ptr[n] = carry;
}

// edge[pos] = {src, bitcast(eattr)} in dst-CSR order.
__global__ void scatter_kernel(const int* __restrict__ src, const int* __restrict__ dst,
                               const float* __restrict__ eattr, const int* __restrict__ row_ptr,
                               int* __restrict__ fill, int2* __restrict__ edge, int E) {
  int e = blockIdx.x * 256 + threadIdx.x;
  if (e >= E) return;
  int d = dst[e];
  int pos = row_ptr[d] + atomicAdd(&fill[d], 1);
  edge[pos] = make_int2(src[e], __float_as_int(eattr[e]));
}

__global__ void selfloop_kernel(const int* __restrict__ deg, const float* __restrict__ asum,
                                const int* __restrict__ row_ptr, int2* __restrict__ edge, int n) {
  int i = blockIdx.x * 256 + threadIdx.x;
  if (i >= n) return;
  int d = deg[i];
  int pos = row_ptr[i] + d;  // self loop last in row
  edge[pos] = make_int2(i, __float_as_int(asum[i] / fmaxf((float)d, 1.f)));
}

// wedot[0..3]=layer0 heads, [4..7]=layer1 heads, [8]=layer2
__global__ void wedot_kernel(const float* __restrict__ We0, const float* __restrict__ ae0,
                             const float* __restrict__ We1, const float* __restrict__ ae1,
                             const float* __restrict__ We2, const float* __restrict__ ae2,
                             float* __restrict__ wedot) {
  int c = threadIdx.x;
  for (int h = 0; h < 4; h++) {
    float v = wave_sum(We0[h * 64 + c] * ae0[h * 64 + c]);
    if (c == 0) wedot[h] = v;
  }
  for (int h = 0; h < 4; h++) {
    float v = wave_sum(We1[h * 64 + c] * ae1[h * 64 + c]);
    if (c == 0) wedot[4 + h] = v;
  }
  float v = wave_sum(We2[c] * ae2[c]);
  if (c == 0) wedot[8] = v;
}

// Reorder W[K=256, M] f32 -> bf16 fragment order for 16x16x32 MFMA B-operand.
template <int M>
__global__ void wreorder_kernel(const float* __restrict__ W, unsigned short* __restrict__ Wf) {
  int idx = blockIdx.x * 256 + threadIdx.x;
  if (idx >= M * 256) return;
  int j = idx & 7, lane = (idx >> 3) & 63, ks = (idx >> 9) & 7, nt = idx >> 12;
  int k = ks * 32 + (lane >> 4) * 8 + j;
  int ncol = nt * 16 + (lane & 15);
  Wf[idx] = f2bf(W[(size_t)k * M + ncol]);
}

// f32 GEMM for layer 0 (K=16): bf16 out + fused head dots.
template <int K, int M, int H>
__global__ __launch_bounds__(256) void gemm_dots_kernel(
    const float* __restrict__ in, const float* __restrict__ W,
    const float* __restrict__ a_s, const float* __restrict__ a_d,
    unsigned short* __restrict__ out, float* __restrict__ al_s, float* __restrict__ al_d,
    int n) {
  constexpr int CT = M / 64;
  constexpr int ROWS = 32;
  constexpr int T = 8;
  static_assert(CT == H, "head slice must equal col-tile slot");
  __shared__ float4 lds[ROWS * K / 4];
  int row0 = blockIdx.x * ROWS;
  int tid = threadIdx.x;
  int total4 = ROWS * K / 4;
  const float4* in4 = (const float4*)(in + (size_t)row0 * K);
  if (row0 + ROWS <= n) {
    for (int i = tid; i < total4; i += 256) lds[i] = in4[i];
  } else {
    float4 z = make_float4(0.f, 0.f, 0.f, 0.f);
    for (int i = tid; i < total4; i += 256) {
      int r = row0 + (i * 4) / K;
      lds[i] = (r < n) ? in4[i] : z;
    }
  }
  __syncthreads();
  int c0 = tid & 63;
  int rg = tid >> 6;
  float acc[T][CT];
#pragma unroll
  for (int t = 0; t < T; t++)
#pragma unroll
    for (int c = 0; c < CT; c++) acc[t][c] = 0.f;

  for (int k4 = 0; k4 < K; k4 += 4) {
    float wv[4][CT];
#pragma unroll
    for (int kk = 0; kk < 4; kk++)
#pragma unroll
      for (int c = 0; c < CT; c++) wv[kk][c] = W[(size_t)(k4 + kk) * M + c0 + 64 * c];
#pragma unroll
    for (int t = 0; t < T; t++) {
      float4 xv = lds[(rg * T + t) * (K / 4) + (k4 >> 2)];
      const float* xs = (const float*)&xv;
#pragma unroll
      for (int kk = 0; kk < 4; kk++)
#pragma unroll
        for (int c = 0; c < CT; c++) acc[t][c] = fmaf(xs[kk], wv[kk][c], acc[t][c]);
    }
  }
#pragma unroll
  for (int t = 0; t < T; t++) {
    int r = row0 + rg * T + t;
    if (r < n) {
#pragma unroll
      for (int c = 0; c < CT; c++) out[(size_t)r * M + c0 + 64 * c] = f2bf(acc[t][c]);
#pragma unroll
      for (int h = 0; h < H; h++) {
        float vs = acc[t][h] * a_s[h * 64 + c0];
        float vd = acc[t][h] * a_d[h * 64 + c0];
#pragma unroll
        for (int off = 32; off > 0; off >>= 1) {
          vs += __shfl_xor(vs, off, 64);
          vd += __shfl_xor(vd, off, 64);
        }
        if (c0 == 0) {
          al_s[(size_t)r * H + h] = vs;
          al_d[(size_t)r * H + h] = vd;
        }
      }
    }
  }
}

// bf16 MFMA GEMM (K=256): bf16 out + fused head dots. One wave / 16-row strip.
template <int M, int H>
__global__ __launch_bounds__(64) void mfma_gemm_dots(
    const unsigned short* __restrict__ Abf, const unsigned short* __restrict__ Wfrag,
    const float* __restrict__ a_s, const float* __restrict__ a_d,
    unsigned short* __restrict__ out, float* __restrict__ al_s, float* __restrict__ al_d,
    int n) {
  int lane = threadIdx.x;
  int row0 = blockIdx.x * 16;
  int m = lane & 15, q = lane >> 4;

  short8 afrag[8];
  int r = row0 + m;
  if (r < n) {
    const short8* arow = (const short8*)(Abf + (size_t)r * 256);
#pragma unroll
    for (int ks = 0; ks < 8; ks++) afrag[ks] = arow[ks * 4 + q];
  } else {
#pragma unroll
    for (int ks = 0; ks < 8; ks++) afrag[ks] = (short8)0;
  }

  float ps[4] = {0.f, 0.f, 0.f, 0.f}, pd[4] = {0.f, 0.f, 0.f, 0.f};
  const short8* wf = (const short8*)Wfrag;

  auto epi = [&](int tile, float4v acc) {
    int col = tile * 16 + m;
    float asv = a_s[col], adv = a_d[col];
#pragma unroll
    for (int reg = 0; reg < 4; reg++) {
      int rr = row0 + q * 4 + reg;
      if (rr < n) out[(size_t)rr * M + col] = f2bf(acc[reg]);
      ps[reg] = fmaf(acc[reg], asv, ps[reg]);
      pd[reg] = fmaf(acc[reg], adv, pd[reg]);
    }
    if ((tile & 3) == 3) {
      int h = tile >> 2;
#pragma unroll
      for (int reg = 0; reg < 4; reg++) {
        float vs = ps[reg], vd = pd[reg];
#pragma unroll
        for (int off = 1; off < 16; off <<= 1) {
          vs += __shfl_xor(vs, off, 64);
          vd += __shfl_xor(vd, off, 64);
        }
        if (m == 0) {
          int rr = row0 + q * 4 + reg;
          if (rr < n) {
            al_s[(size_t)rr * H + h] = vs;
            al_d[(size_t)rr * H + h] = vd;
          }
        }
        ps[reg] = 0.f;
        pd[reg] = 0.f;
      }
    }
  };

  for (int nt = 0; nt < M / 16; nt += 2) {
    const short8* b0 = wf + (size_t)nt * 8 * 64 + lane;
    const short8* b1 = b0 + 8 * 64;
    short8 bf0[8], bf1[8];
#pragma unroll
    for (int ks = 0; ks < 8; ks++) {
      bf0[ks] = b0[ks * 64];
      bf1[ks] = b1[ks * 64];
    }
    float4v acc0 = {0.f, 0.f, 0.f, 0.f};
    float4v acc1 = {0.f, 0.f, 0.f, 0.f};
#pragma unroll
    for (int ks = 0; ks < 8; ks++) {
      acc0 = __builtin_amdgcn_mfma_f32_16x16x32_bf16(afrag[ks], bf0[ks], acc0, 0, 0, 0);
      acc1 = __builtin_amdgcn_mfma_f32_16x16x32_bf16(afrag[ks], bf1[ks], acc1, 0, 0, 0);
    }
    epi(nt, acc0);
    epi(nt + 1, acc1);
  }
}

// H=4 aggregation, chunk-4 edge loop (4 independent row gathers in flight).
// One wave/node; lane c holds channels 4c..4c+3, head = c>>4. B bf16.
__global__ __launch_bounds__(256) void agg4_kernel(
    const int* __restrict__ row_ptr, const int2* __restrict__ edge,
    const float* __restrict__ al_s, const float* __restrict__ al_d,
    const float* __restrict__ wedot, const unsigned short* __restrict__ B,
    const float* __restrict__ bias, unsigned short* __restrict__ out, int n) {
  int node = blockIdx.x * 4 + (threadIdx.x >> 6);
  int c = threadIdx.x & 63;
  if (node >= n) return;
  int h4 = c >> 4;
  float wd = wedot[h4];
  float adn = al_d[(size_t)node * 4 + h4];
  int beg = row_ptr[node], end = row_ptr[node + 1];
  const ushort4* Bp = (const ushort4*)B;
  float4 acc = make_float4(0.f, 0.f, 0.f, 0.f);
  float den = 0.f;
  int e = beg;
  for (; e + 4 <= end; e += 4) {
    int2 g0 = edge[e], g1 = edge[e + 1], g2 = edge[e + 2], g3 = edge[e + 3];
    float a0 = al_s[(size_t)g0.x * 4 + h4];
    float a1 = al_s[(size_t)g1.x * 4 + h4];
    float a2 = al_s[(size_t)g2.x * 4 + h4];
    float a3 = al_s[(size_t)g3.x * 4 + h4];
    ushort4 b0 = Bp[(size_t)g0.x * 64 + c];
    ushort4 b1 = Bp[(size_t)g1.x * 64 + c];
    ushort4 b2 = Bp[(size_t)g2.x * 64 + c];
    ushort4 b3 = Bp[(size_t)g3.x * 64 + c];
    float w0 = edge_w(a0 + adn + __int_as_float(g0.y) * wd);
    float w1 = edge_w(a1 + adn + __int_as_float(g1.y) * wd);
    float w2 = edge_w(a2 + adn + __int_as_float(g2.y) * wd);
    float w3 = edge_w(a3 + adn + __int_as_float(g3.y) * wd);
    den += (w0 + w1) + (w2 + w3);
    acc.x = fmaf(w0, bf2f(b0.x), acc.x);
    acc.y = fmaf(w0, bf2f(b0.y), acc.y);
    acc.z = fmaf(w0, bf2f(b0.z), acc.z);
    acc.w = fmaf(w0, bf2f(b0.w), acc.w);
    acc.x = fmaf(w1, bf2f(b1.x), acc.x);
    acc.y = fmaf(w1, bf2f(b1.y), acc.y);
    acc.z = fmaf(w1, bf2f(b1.z), acc.z);
    acc.w = fmaf(w1, bf2f(b1.w), acc.w);
    acc.x = fmaf(w2, bf2f(b2.x), acc.x);
    acc.y = fmaf(w2, bf2f(b2.y), acc.y);
    acc.z = fmaf(w2, bf2f(b2.z), acc.z);
    acc.w = fmaf(w2, bf2f(b2.w), acc.w);
    acc.x = fmaf(w3, bf2f(b3.x), acc.x);
    acc.y = fmaf(w3, bf2f(b3.y), acc.y);
    acc.z = fmaf(w3, bf2f(b3.z), acc.z);
    acc.w = fmaf(w3, bf2f(b3.w), acc.w);
  }
  for (; e < end; e++) {
    int2 g = edge[e];
    float als = al_s[(size_t)g.x * 4 + h4];
    ushort4 bv = Bp[(size_t)g.x * 64 + c];
    float w = edge_w(als + adn + __int_as_float(g.y) * wd);
    den += w;
    acc.x = fmaf(w, bf2f(bv.x), acc.x);
    acc.y = fmaf(w, bf2f(bv.y), acc.y);
    acc.z = fmaf(w, bf2f(bv.z), acc.z);
    acc.w = fmaf(w, bf2f(bv.w), acc.w);
  }
  float inv = 1.f / (den + 1e-16f);
  float4 b4 = ((const float4*)bias)[c];
  float ox = acc.x * inv + b4.x;
  float oy = acc.y * inv + b4.y;
  float oz = acc.z * inv + b4.z;
  float ow = acc.w * inv + b4.w;
  ox = ox > 0.f ? ox : expm1f(ox);
  oy = oy > 0.f ? oy : expm1f(oy);
  oz = oz > 0.f ? oz : expm1f(oz);
  ow = ow > 0.f ? ow : expm1f(ow);
  ushort4 o4;
  o4.x = f2bf(ox);
  o4.y = f2bf(oy);
  o4.z = f2bf(oz);
  o4.w = f2bf(ow);
  ((ushort4*)out)[(size_t)node * 64 + c] = o4;
}

// H=1 aggregation, chunk-8 edge loop, + bias + LayerNorm fused; one wave/node.
__global__ __launch_bounds__(256) void agg_ln_kernel(
    const int* __restrict__ row_ptr, const int2* __restrict__ edge,
    const float* __restrict__ al_s, const float* __restrict__ al_d,
    const float* __restrict__ wedot, const unsigned short* __restrict__ B,
    const float* __restrict__ bias, const float* __restrict__ ln_g,
    const float* __restrict__ ln_b, float* __restrict__ out, int n) {
  int node = blockIdx.x * 4 + (threadIdx.x >> 6);
  int c = threadIdx.x & 63;
  if (node >= n) return;
  float wd = wedot[0];
  float adn = al_d[node];
  int beg = row_ptr[node], end = row_ptr[node + 1];
  float acc = 0.f, den = 0.f;
  int e = beg;
  for (; e + 8 <= end; e += 8) {
    int2 g[8];
    float als[8];
    unsigned short bv[8];
#pragma unroll
    for (int i = 0; i < 8; i++) g[i] = edge[e + i];
#pragma unroll
    for (int i = 0; i < 8; i++) als[i] = al_s[g[i].x];
#pragma unroll
    for (int i = 0; i < 8; i++) bv[i] = B[(size_t)g[i].x * 64 + c];
#pragma unroll
    for (int i = 0; i < 8; i++) {
      float wgt = edge_w(als[i] + adn + __int_as_float(g[i].y) * wd);
      den += wgt;
      acc = fmaf(wgt, bf2f(bv[i]), acc);
    }
  }
  for (; e < end; e++) {
    int2 g = edge[e];
    float als = al_s[g.x];
    unsigned short bv = B[(size_t)g.x * 64 + c];
    float wgt = edge_w(als + adn + __int_as_float(g.y) * wd);
    den += wgt;
    acc = fmaf(wgt, bf2f(bv), acc);
  }
  float o = acc / (den + 1e-16f) + bias[c];
  float mu = wave_sum(o) * (1.f / 64.f);
  float dv = o - mu;
  float var = wave_sum(dv * dv) * (1.f / 64.f);
  out[(size_t)node * 64 + c] = dv * rsqrtf(var + 1e-5f) * ln_g[c] + ln_b[c];
}

extern "C" void kernel_launch(void* const* d_in, const int* in_sizes, int n_in,
                              void* d_out, int out_size, void* d_ws, size_t ws_size,
                              hipStream_t stream) {
  const float* x = (const float*)d_in[0];
  const int* ei = (const int*)d_in[1];
  const float* eattr = (const float*)d_in[2];
  const float* W0 = (const float*)d_in[3];
  const float* as0 = (const float*)d_in[4];
  const float* ad0 = (const float*)d_in[5];
  const float* We0 = (const float*)d_in[6];
  const float* ae0 = (const float*)d_in[7];
  const float* b0 = (const float*)d_in[8];
  const float* W1 = (const float*)d_in[9];
  const float* as1 = (const float*)d_in[10];
  const float* ad1 = (const float*)d_in[11];
  const float* We1 = (const float*)d_in[12];
  const float* ae1 = (const float*)d_in[13];
  const float* b1 = (const float*)d_in[14];
  const float* W2 = (const float*)d_in[15];
  const float* as2 = (const float*)d_in[16];
  const float* ad2 = (const float*)d_in[17];
  const float* We2 = (const float*)d_in[18];
  const float* ae2 = (const float*)d_in[19];
  const float* b2 = (const float*)d_in[20];
  const float* lng = (const float*)d_in[21];
  const float* lnb = (const float*)d_in[22];
  float* outp = (float*)d_out;

  const int N = in_sizes[0] / 16;
  const int E = in_sizes[1] / 2;
  const int P = E + N;
  const int* srcv = ei;
  const int* dstv = ei + E;

  char* w = (char*)d_ws;
  size_t off = 0;
  auto alloc = [&](size_t bytes) -> void* {
    void* p = w + off;
    off += (bytes + 255) & ~(size_t)255;
    return p;
  };
  int* deg = (int*)alloc((size_t)N * 4);
  float* asum = (float*)alloc((size_t)N * 4);
  int* fill = (int*)alloc((size_t)N * 4);
  size_t zero_bytes = off;
  int* row_ptr = (int*)alloc((size_t)(N + 1) * 4);
  int2* edge = (int2*)alloc((size_t)P * 8);
  float* wedot = (float*)alloc(16 * 4);
  float* al_s = (float*)alloc((size_t)N * 4 * 4);
  float* al_d = (float*)alloc((size_t)N * 4 * 4);
  unsigned short* Wf1 = (unsigned short*)alloc(256 * 256 * 2);
  unsigned short* Wf2 = (unsigned short*)alloc(256 * 64 * 2);
  unsigned short* bufA = (unsigned short*)alloc((size_t)N * 256 * 2);  // agg out
  unsigned short* bufB = (unsigned short*)alloc((size_t)N * 256 * 2);  // gemm out
  (void)ws_size;

  hipMemsetAsync(d_ws, 0, zero_bytes, stream);

  int gE = (E + 255) / 256;
  int gN = (N + 255) / 256;
  deg_kernel<<<gE, 256, 0, stream>>>(dstv, eattr, deg, asum, E);
  scan_kernel<<<1, 1024, 0, stream>>>(deg, row_ptr, N);
  scatter_kernel<<<gE, 256, 0, stream>>>(srcv, dstv, eattr, row_ptr, fill, edge, E);
  selfloop_kernel<<<gN, 256, 0, stream>>>(deg, asum, row_ptr, edge, N);
  wedot_kernel<<<1, 64, 0, stream>>>(We0, ae0, We1, ae1, We2, ae2, wedot);
  wreorder_kernel<256><<<256, 256, 0, stream>>>(W1, Wf1);
  wreorder_kernel<64><<<64, 256, 0, stream>>>(W2, Wf2);

  int gGemm0 = (N + 31) / 32;
  int gStrip = (N + 15) / 16;
  int gNode4 = (N + 3) / 4;

  // ---- layer 0
  gemm_dots_kernel<16, 256, 4><<<gGemm0, 256, 0, stream>>>(x, W0, as0, ad0, bufB, al_s, al_d, N);
  agg4_kernel<<<gNode4, 256, 0, stream>>>(row_ptr, edge, al_s, al_d, wedot, bufB, b0, bufA, N);

  // ---- layer 1
  mfma_gemm_dots<256, 4><<<gStrip, 64, 0, stream>>>(bufA, Wf1, as1, ad1, bufB, al_s, al_d, N);
  agg4_kernel<<<gNode4, 256, 0, stream>>>(row_ptr, edge, al_s, al_d, wedot + 4, bufB, b1, bufA, N);

  // ---- layer 2 (+ LayerNorm -> d_out)
  mfma_gemm_dots<64, 1><<<gStrip, 64, 0, stream>>>(bufA, Wf2, as2, ad2, bufB, al_s, al_d, N);
  agg_ln_kernel<<<gNode4, 256, 0, stream>>>(row_ptr, edge, al_s, al_d, wedot + 8, bufB, b2,
                                            lng, lnb, outp, N);
}

// Round 6
// 311.376 us; speedup vs baseline: 1.6321x; 1.0214x over previous
//
#include <hip/hip_runtime.h>
#include <hip/hip_bf16.h>
#include <math.h>

// GAT x3 + LayerNorm for MI355X (gfx950).
// R6: attention dots computed as al = A @ va (va = W contracted with a_s/a_d,
// precomputed) -> no shuffle reductions anywhere. MFMA GEMMs carry va as one
// extra fragment col-tile; layer-0 al via tiny per-node kernel. agg4 chunk-8.
// Carried: bf16 h end-to-end, inline exp weights, int2 edge records.

typedef __attribute__((ext_vector_type(8))) short short8;
typedef __attribute__((ext_vector_type(4))) float float4v;

__device__ __forceinline__ float wave_sum(float v) {
#pragma unroll
  for (int off = 32; off > 0; off >>= 1) v += __shfl_xor(v, off, 64);
  return v;
}

__device__ __forceinline__ unsigned short f2bf(float v) {
  unsigned u = __float_as_uint(v);
  unsigned r = u + 0x7fff + ((u >> 16) & 1);  // RNE
  return (unsigned short)(r >> 16);
}

__device__ __forceinline__ float bf2f(unsigned short u) {
  return __uint_as_float(((unsigned)u) << 16);
}

// leaky_relu(0.2) + clamp + exp (softmax max cancels in the ratio)
__device__ __forceinline__ float edge_w(float a) {
  a = fmaxf(a, 0.2f * a);
  a = fminf(a, 30.f);
  return __expf(a);
}

__global__ void deg_kernel(const int* __restrict__ dst, const float* __restrict__ eattr,
                           int* __restrict__ deg, float* __restrict__ asum, int E) {
  int e = blockIdx.x * 256 + threadIdx.x;
  if (e >= E) return;
  int d = dst[e];
  atomicAdd(&deg[d], 1);
  atomicAdd(&asum[d], eattr[e]);
}

// row_ptr = exclusive scan of (deg[i]+1); single block, shfl-based.
__global__ __launch_bounds__(1024) void scan_kernel(const int* __restrict__ deg,
                                                    int* __restrict__ row_ptr, int n) {
  __shared__ int wexc[16];
  __shared__ int carry, chunk_tot;
  int tid = threadIdx.x, wid = tid >> 6, lane = tid & 63;
  if (tid == 0) carry = 0;
  __syncthreads();
  for (int base = 0; base < n; base += 1024) {
    int i = base + tid;
    int v = (i < n) ? (deg[i] + 1) : 0;
    int sc = v;
#pragma unroll
    for (int off = 1; off < 64; off <<= 1) {
      int t = __shfl_up(sc, off, 64);
      if (lane >= off) sc += t;
    }
    if (lane == 63) wexc[wid] = sc;
    __syncthreads();
    if (tid == 0) {
      int run = 0;
#pragma unroll
      for (int wI = 0; wI < 16; wI++) { int t = wexc[wI]; wexc[wI] = run; run += t; }
      chunk_tot = run;
    }
    __syncthreads();
    if (i < n) row_ptr[i] = carry + wexc[wid] + sc - v;
    __syncthreads();
    if (tid == 0) carry += chunk_tot;
    __syncthreads();
  }
  if (threadIdx.x == 0) row_ptr[n] = carry;
}

// edge[pos] = {src, bitcast(eattr)} in dst-CSR order.
__global__ void scatter_kernel(const int* __restrict__ src, const int* __restrict__ dst,
                               const float* __restrict__ eattr, const int* __restrict__ row_ptr,
                               int* __restrict__ fill, int2* __restrict__ edge, int E) {
  int e = blockIdx.x * 256 + threadIdx.x;
  if (e >= E) return;
  int d = dst[e];
  int pos = row_ptr[d] + atomicAdd(&fill[d], 1);
  edge[pos] = make_int2(src[e], __float_as_int(eattr[e]));
}

__global__ void selfloop_kernel(const int* __restrict__ deg, const float* __restrict__ asum,
                                const int* __restrict__ row_ptr, int2* __restrict__ edge, int n) {
  int i = blockIdx.x * 256 + threadIdx.x;
  if (i >= n) return;
  int d = deg[i];
  int pos = row_ptr[i] + d;  // self loop last in row
  edge[pos] = make_int2(i, __float_as_int(asum[i] / fmaxf((float)d, 1.f)));
}

// wedot[0..3]=layer0 heads, [4..7]=layer1 heads, [8]=layer2
__global__ void wedot_kernel(const float* __restrict__ We0, const float* __restrict__ ae0,
                             const float* __restrict__ We1, const float* __restrict__ ae1,
                             const float* __restrict__ We2, const float* __restrict__ ae2,
                             float* __restrict__ wedot) {
  int c = threadIdx.x;
  for (int h = 0; h < 4; h++) {
    float v = wave_sum(We0[h * 64 + c] * ae0[h * 64 + c]);
    if (c == 0) wedot[h] = v;
  }
  for (int h = 0; h < 4; h++) {
    float v = wave_sum(We1[h * 64 + c] * ae1[h * 64 + c]);
    if (c == 0) wedot[4 + h] = v;
  }
  float v = wave_sum(We2[c] * ae2[c]);
  if (c == 0) wedot[8] = v;
}

// va[k][col]: col<H -> sum_c W[k,col*64+c]*a_s[col,c]; col<2H -> a_d; else 0.
template <int K, int M, int H>
__global__ void vabuild_kernel(const float* __restrict__ W, const float* __restrict__ a_s,
                               const float* __restrict__ a_d, float* __restrict__ va) {
  int idx = blockIdx.x * 256 + threadIdx.x;
  if (idx >= K * 16) return;
  int col = idx & 15, k = idx >> 4;
  float v = 0.f;
  if (col < H) {
    for (int c = 0; c < 64; c++) v = fmaf(W[(size_t)k * M + col * 64 + c], a_s[col * 64 + c], v);
  } else if (col < 2 * H) {
    int h = col - H;
    for (int c = 0; c < 64; c++) v = fmaf(W[(size_t)k * M + h * 64 + c], a_d[h * 64 + c], v);
  }
  va[idx] = v;
}

// Layer-0 attention dots: al[r,h] = x[r,:16] @ va0[:,h]. One thread per node.
__global__ void dots0_kernel(const float* __restrict__ x, const float* __restrict__ va,
                             float* __restrict__ al_s, float* __restrict__ al_d, int n) {
  int r = blockIdx.x * 256 + threadIdx.x;
  if (r >= n) return;
  const float* xr = x + (size_t)r * 16;
  float s0 = 0, s1 = 0, s2 = 0, s3 = 0, d0 = 0, d1 = 0, d2 = 0, d3 = 0;
#pragma unroll
  for (int k = 0; k < 16; k++) {
    float xv = xr[k];
    const float* vk = va + k * 16;
    s0 = fmaf(xv, vk[0], s0);
    s1 = fmaf(xv, vk[1], s1);
    s2 = fmaf(xv, vk[2], s2);
    s3 = fmaf(xv, vk[3], s3);
    d0 = fmaf(xv, vk[4], d0);
    d1 = fmaf(xv, vk[5], d1);
    d2 = fmaf(xv, vk[6], d2);
    d3 = fmaf(xv, vk[7], d3);
  }
  ((float4*)al_s)[r] = make_float4(s0, s1, s2, s3);
  ((float4*)al_d)[r] = make_float4(d0, d1, d2, d3);
}

// Reorder W[K=256,M] f32 -> bf16 fragment order for 16x16x32 MFMA B-operand,
// with one extra col-tile (index M/16) holding va (al_s/al_d columns).
template <int M>
__global__ void wreorder_kernel(const float* __restrict__ W, const float* __restrict__ va,
                                unsigned short* __restrict__ Wf) {
  constexpr int NT = M / 16 + 1;
  int idx = blockIdx.x * 256 + threadIdx.x;
  if (idx >= NT * 4096) return;
  int j = idx & 7, lane = (idx >> 3) & 63, ks = (idx >> 9) & 7, nt = idx >> 12;
  int k = ks * 32 + (lane >> 4) * 8 + j;
  int col = lane & 15;
  float v = (nt < M / 16) ? W[(size_t)k * M + nt * 16 + col] : va[k * 16 + col];
  Wf[idx] = f2bf(v);
}

// f32 GEMM for layer 0 (K=16): bf16 out, no epilogue dots. 16 rows/block.
template <int K, int M>
__global__ __launch_bounds__(256) void gemm0_kernel(const float* __restrict__ in,
                                                    const float* __restrict__ W,
                                                    unsigned short* __restrict__ out, int n) {
  constexpr int CT = M / 64;
  constexpr int ROWS = 16;
  constexpr int T = 4;
  __shared__ float4 lds[ROWS * K / 4];
  int row0 = blockIdx.x * ROWS;
  int tid = threadIdx.x;
  int total4 = ROWS * K / 4;
  const float4* in4 = (const float4*)(in + (size_t)row0 * K);
  if (row0 + ROWS <= n) {
    for (int i = tid; i < total4; i += 256) lds[i] = in4[i];
  } else {
    float4 z = make_float4(0.f, 0.f, 0.f, 0.f);
    for (int i = tid; i < total4; i += 256) {
      int r = row0 + (i * 4) / K;
      lds[i] = (r < n) ? in4[i] : z;
    }
  }
  __syncthreads();
  int c0 = tid & 63;
  int rg = tid >> 6;
  float acc[T][CT];
#pragma unroll
  for (int t = 0; t < T; t++)
#pragma unroll
    for (int c = 0; c < CT; c++) acc[t][c] = 0.f;

#pragma unroll
  for (int k4 = 0; k4 < K; k4 += 4) {
    float wv[4][CT];
#pragma unroll
    for (int kk = 0; kk < 4; kk++)
#pragma unroll
      for (int c = 0; c < CT; c++) wv[kk][c] = W[(size_t)(k4 + kk) * M + c0 + 64 * c];
#pragma unroll
    for (int t = 0; t < T; t++) {
      float4 xv = lds[(rg * T + t) * (K / 4) + (k4 >> 2)];
      const float* xs = (const float*)&xv;
#pragma unroll
      for (int kk = 0; kk < 4; kk++)
#pragma unroll
        for (int c = 0; c < CT; c++) acc[t][c] = fmaf(xs[kk], wv[kk][c], acc[t][c]);
    }
  }
#pragma unroll
  for (int t = 0; t < T; t++) {
    int r = row0 + rg * T + t;
    if (r < n) {
#pragma unroll
      for (int c = 0; c < CT; c++) out[(size_t)r * M + c0 + 64 * c] = f2bf(acc[t][c]);
    }
  }
}

// bf16 MFMA GEMM (K=256): bf16 out; al_s/al_d from the extra va col-tile
// (C-layout direct stores, no shuffles). One wave per 16-row strip.
template <int M, int H>
__global__ __launch_bounds__(64) void mfma_gemm_dots(
    const unsigned short* __restrict__ Abf, const unsigned short* __restrict__ Wfrag,
    unsigned short* __restrict__ out, float* __restrict__ al_s, float* __restrict__ al_d,
    int n) {
  int lane = threadIdx.x;
  int row0 = blockIdx.x * 16;
  int m = lane & 15, q = lane >> 4;

  short8 afrag[8];
  int r = row0 + m;
  if (r < n) {
    const short8* arow = (const short8*)(Abf + (size_t)r * 256);
#pragma unroll
    for (int ks = 0; ks < 8; ks++) afrag[ks] = arow[ks * 4 + q];
  } else {
#pragma unroll
    for (int ks = 0; ks < 8; ks++) afrag[ks] = (short8)0;
  }

  const short8* wf = (const short8*)Wfrag;

  auto epi = [&](int tile, float4v acc) {
    int col = tile * 16 + m;
#pragma unroll
    for (int reg = 0; reg < 4; reg++) {
      int rr = row0 + q * 4 + reg;
      if (rr < n) out[(size_t)rr * M + col] = f2bf(acc[reg]);
    }
  };

  for (int nt = 0; nt < M / 16; nt += 2) {
    const short8* b0 = wf + (size_t)nt * 8 * 64 + lane;
    const short8* b1 = b0 + 8 * 64;
    short8 bf0[8], bf1[8];
#pragma unroll
    for (int ks = 0; ks < 8; ks++) {
      bf0[ks] = b0[ks * 64];
      bf1[ks] = b1[ks * 64];
    }
    float4v acc0 = {0.f, 0.f, 0.f, 0.f};
    float4v acc1 = {0.f, 0.f, 0.f, 0.f};
#pragma unroll
    for (int ks = 0; ks < 8; ks++) {
      acc0 = __builtin_amdgcn_mfma_f32_16x16x32_bf16(afrag[ks], bf0[ks], acc0, 0, 0, 0);
      acc1 = __builtin_amdgcn_mfma_f32_16x16x32_bf16(afrag[ks], bf1[ks], acc1, 0, 0, 0);
    }
    epi(nt, acc0);
    epi(nt + 1, acc1);
  }

  // va tile -> al_s / al_d
  {
    const short8* bl = wf + (size_t)(M / 16) * 8 * 64 + lane;
    short8 bf[8];
#pragma unroll
    for (int ks = 0; ks < 8; ks++) bf[ks] = bl[ks * 64];
    float4v acc = {0.f, 0.f, 0.f, 0.f};
#pragma unroll
    for (int ks = 0; ks < 8; ks++)
      acc = __builtin_amdgcn_mfma_f32_16x16x32_bf16(afrag[ks], bf[ks], acc, 0, 0, 0);
#pragma unroll
    for (int reg = 0; reg < 4; reg++) {
      int rr = row0 + q * 4 + reg;
      if (rr < n) {
        if (m < H) al_s[(size_t)rr * H + m] = acc[reg];
        else if (m < 2 * H) al_d[(size_t)rr * H + (m - H)] = acc[reg];
      }
    }
  }
}

// H=4 aggregation, chunk-8/4 edge loop. One wave/node; lane c holds channels
// 4c..4c+3, head = c>>4. B bf16. bias+ELU fused; writes bf16.
__global__ __launch_bounds__(256) void agg4_kernel(
    const int* __restrict__ row_ptr, const int2* __restrict__ edge,
    const float* __restrict__ al_s, const float* __restrict__ al_d,
    const float* __restrict__ wedot, const unsigned short* __restrict__ B,
    const float* __restrict__ bias, unsigned short* __restrict__ out, int n) {
  int node = blockIdx.x * 4 + (threadIdx.x >> 6);
  int c = threadIdx.x & 63;
  if (node >= n) return;
  int h4 = c >> 4;
  float wd = wedot[h4];
  float adn = al_d[(size_t)node * 4 + h4];
  int beg = row_ptr[node], end = row_ptr[node + 1];
  const ushort4* Bp = (const ushort4*)B;
  float4 acc = make_float4(0.f, 0.f, 0.f, 0.f);
  float den = 0.f;
  int e = beg;
  for (; e + 8 <= end; e += 8) {
    int2 g[8];
    float al[8];
    ushort4 b[8];
#pragma unroll
    for (int i = 0; i < 8; i++) g[i] = edge[e + i];
#pragma unroll
    for (int i = 0; i < 8; i++) al[i] = al_s[(size_t)g[i].x * 4 + h4];
#pragma unroll
    for (int i = 0; i < 8; i++) b[i] = Bp[(size_t)g[i].x * 64 + c];
#pragma unroll
    for (int i = 0; i < 8; i++) {
      float w = edge_w(al[i] + adn + __int_as_float(g[i].y) * wd);
      den += w;
      acc.x = fmaf(w, bf2f(b[i].x), acc.x);
      acc.y = fmaf(w, bf2f(b[i].y), acc.y);
      acc.z = fmaf(w, bf2f(b[i].z), acc.z);
      acc.w = fmaf(w, bf2f(b[i].w), acc.w);
    }
  }
  for (; e + 4 <= end; e += 4) {
    int2 g[4];
    float al[4];
    ushort4 b[4];
#pragma unroll
    for (int i = 0; i < 4; i++) g[i] = edge[e + i];
#pragma unroll
    for (int i = 0; i < 4; i++) al[i] = al_s[(size_t)g[i].x * 4 + h4];
#pragma unroll
    for (int i = 0; i < 4; i++) b[i] = Bp[(size_t)g[i].x * 64 + c];
#pragma unroll
    for (int i = 0; i < 4; i++) {
      float w = edge_w(al[i] + adn + __int_as_float(g[i].y) * wd);
      den += w;
      acc.x = fmaf(w, bf2f(b[i].x), acc.x);
      acc.y = fmaf(w, bf2f(b[i].y), acc.y);
      acc.z = fmaf(w, bf2f(b[i].z), acc.z);
      acc.w = fmaf(w, bf2f(b[i].w), acc.w);
    }
  }
  for (; e < end; e++) {
    int2 g = edge[e];
    float als = al_s[(size_t)g.x * 4 + h4];
    ushort4 bv = Bp[(size_t)g.x * 64 + c];
    float w = edge_w(als + adn + __int_as_float(g.y) * wd);
    den += w;
    acc.x = fmaf(w, bf2f(bv.x), acc.x);
    acc.y = fmaf(w, bf2f(bv.y), acc.y);
    acc.z = fmaf(w, bf2f(bv.z), acc.z);
    acc.w = fmaf(w, bf2f(bv.w), acc.w);
  }
  float inv = 1.f / (den + 1e-16f);
  float4 b4 = ((const float4*)bias)[c];
  float ox = acc.x * inv + b4.x;
  float oy = acc.y * inv + b4.y;
  float oz = acc.z * inv + b4.z;
  float ow = acc.w * inv + b4.w;
  ox = ox > 0.f ? ox : expm1f(ox);
  oy = oy > 0.f ? oy : expm1f(oy);
  oz = oz > 0.f ? oz : expm1f(oz);
  ow = ow > 0.f ? ow : expm1f(ow);
  ushort4 o4;
  o4.x = f2bf(ox);
  o4.y = f2bf(oy);
  o4.z = f2bf(oz);
  o4.w = f2bf(ow);
  ((ushort4*)out)[(size_t)node * 64 + c] = o4;
}

// H=1 aggregation, chunk-8 edge loop, + bias + LayerNorm fused; one wave/node.
__global__ __launch_bounds__(256) void agg_ln_kernel(
    const int* __restrict__ row_ptr, const int2* __restrict__ edge,
    const float* __restrict__ al_s, const float* __restrict__ al_d,
    const float* __restrict__ wedot, const unsigned short* __restrict__ B,
    const float* __restrict__ bias, const float* __restrict__ ln_g,
    const float* __restrict__ ln_b, float* __restrict__ out, int n) {
  int node = blockIdx.x * 4 + (threadIdx.x >> 6);
  int c = threadIdx.x & 63;
  if (node >= n) return;
  float wd = wedot[0];
  float adn = al_d[node];
  int beg = row_ptr[node], end = row_ptr[node + 1];
  float acc = 0.f, den = 0.f;
  int e = beg;
  for (; e + 8 <= end; e += 8) {
    int2 g[8];
    float als[8];
    unsigned short bv[8];
#pragma unroll
    for (int i = 0; i < 8; i++) g[i] = edge[e + i];
#pragma unroll
    for (int i = 0; i < 8; i++) als[i] = al_s[g[i].x];
#pragma unroll
    for (int i = 0; i < 8; i++) bv[i] = B[(size_t)g[i].x * 64 + c];
#pragma unroll
    for (int i = 0; i < 8; i++) {
      float wgt = edge_w(als[i] + adn + __int_as_float(g[i].y) * wd);
      den += wgt;
      acc = fmaf(wgt, bf2f(bv[i]), acc);
    }
  }
  for (; e < end; e++) {
    int2 g = edge[e];
    float als = al_s[g.x];
    unsigned short bv = B[(size_t)g.x * 64 + c];
    float wgt = edge_w(als + adn + __int_as_float(g.y) * wd);
    den += wgt;
    acc = fmaf(wgt, bf2f(bv), acc);
  }
  float o = acc / (den + 1e-16f) + bias[c];
  float mu = wave_sum(o) * (1.f / 64.f);
  float dv = o - mu;
  float var = wave_sum(dv * dv) * (1.f / 64.f);
  out[(size_t)node * 64 + c] = dv * rsqrtf(var + 1e-5f) * ln_g[c] + ln_b[c];
}

extern "C" void kernel_launch(void* const* d_in, const int* in_sizes, int n_in,
                              void* d_out, int out_size, void* d_ws, size_t ws_size,
                              hipStream_t stream) {
  const float* x = (const float*)d_in[0];
  const int* ei = (const int*)d_in[1];
  const float* eattr = (const float*)d_in[2];
  const float* W0 = (const float*)d_in[3];
  const float* as0 = (const float*)d_in[4];
  const float* ad0 = (const float*)d_in[5];
  const float* We0 = (const float*)d_in[6];
  const float* ae0 = (const float*)d_in[7];
  const float* b0 = (const float*)d_in[8];
  const float* W1 = (const float*)d_in[9];
  const float* as1 = (const float*)d_in[10];
  const float* ad1 = (const float*)d_in[11];
  const float* We1 = (const float*)d_in[12];
  const float* ae1 = (const float*)d_in[13];
  const float* b1 = (const float*)d_in[14];
  const float* W2 = (const float*)d_in[15];
  const float* as2 = (const float*)d_in[16];
  const float* ad2 = (const float*)d_in[17];
  const float* We2 = (const float*)d_in[18];
  const float* ae2 = (const float*)d_in[19];
  const float* b2 = (const float*)d_in[20];
  const float* lng = (const float*)d_in[21];
  const float* lnb = (const float*)d_in[22];
  float* outp = (float*)d_out;

  const int N = in_sizes[0] / 16;
  const int E = in_sizes[1] / 2;
  const int P = E + N;
  const int* srcv = ei;
  const int* dstv = ei + E;

  char* w = (char*)d_ws;
  size_t off = 0;
  auto alloc = [&](size_t bytes) -> void* {
    void* p = w + off;
    off += (bytes + 255) & ~(size_t)255;
    return p;
  };
  int* deg = (int*)alloc((size_t)N * 4);
  float* asum = (float*)alloc((size_t)N * 4);
  int* fill = (int*)alloc((size_t)N * 4);
  size_t zero_bytes = off;
  int* row_ptr = (int*)alloc((size_t)(N + 1) * 4);
  int2* edge = (int2*)alloc((size_t)P * 8);
  float* wedot = (float*)alloc(16 * 4);
  float* al_s = (float*)alloc((size_t)N * 4 * 4);
  float* al_d = (float*)alloc((size_t)N * 4 * 4);
  float* va0 = (float*)alloc(16 * 16 * 4);
  float* va1 = (float*)alloc(256 * 16 * 4);
  float* va2 = (float*)alloc(256 * 16 * 4);
  unsigned short* Wf1 = (unsigned short*)alloc((size_t)17 * 4096 * 2);
  unsigned short* Wf2 = (unsigned short*)alloc((size_t)5 * 4096 * 2);
  unsigned short* bufA = (unsigned short*)alloc((size_t)N * 256 * 2);  // agg out
  unsigned short* bufB = (unsigned short*)alloc((size_t)N * 256 * 2);  // gemm out
  (void)ws_size;

  hipMemsetAsync(d_ws, 0, zero_bytes, stream);

  int gE = (E + 255) / 256;
  int gN = (N + 255) / 256;
  deg_kernel<<<gE, 256, 0, stream>>>(dstv, eattr, deg, asum, E);
  scan_kernel<<<1, 1024, 0, stream>>>(deg, row_ptr, N);
  scatter_kernel<<<gE, 256, 0, stream>>>(srcv, dstv, eattr, row_ptr, fill, edge, E);
  selfloop_kernel<<<gN, 256, 0, stream>>>(deg, asum, row_ptr, edge, N);
  wedot_kernel<<<1, 64, 0, stream>>>(We0, ae0, We1, ae1, We2, ae2, wedot);
  vabuild_kernel<16, 256, 4><<<1, 256, 0, stream>>>(W0, as0, ad0, va0);
  vabuild_kernel<256, 256, 4><<<16, 256, 0, stream>>>(W1, as1, ad1, va1);
  vabuild_kernel<256, 64, 1><<<16, 256, 0, stream>>>(W2, as2, ad2, va2);
  wreorder_kernel<256><<<(17 * 4096 + 255) / 256, 256, 0, stream>>>(W1, va1, Wf1);
  wreorder_kernel<64><<<(5 * 4096 + 255) / 256, 256, 0, stream>>>(W2, va2, Wf2);

  int gGemm0 = (N + 15) / 16;
  int gStrip = (N + 15) / 16;
  int gNode4 = (N + 3) / 4;

  // ---- layer 0
  dots0_kernel<<<gN, 256, 0, stream>>>(x, va0, al_s, al_d, N);
  gemm0_kernel<16, 256><<<gGemm0, 256, 0, stream>>>(x, W0, bufB, N);
  agg4_kernel<<<gNode4, 256, 0, stream>>>(row_ptr, edge, al_s, al_d, wedot, bufB, b0, bufA, N);

  // ---- layer 1
  mfma_gemm_dots<256, 4><<<gStrip, 64, 0, stream>>>(bufA, Wf1, bufB, al_s, al_d, N);
  agg4_kernel<<<gNode4, 256, 0, stream>>>(row_ptr, edge, al_s, al_d, wedot + 4, bufB, b1, bufA, N);

  // ---- layer 2 (+ LayerNorm -> d_out)
  mfma_gemm_dots<64, 1><<<gStrip, 64, 0, stream>>>(bufA, Wf2, bufB, al_s, al_d, N);
  agg_ln_kernel<<<gNode4, 256, 0, stream>>>(row_ptr, edge, al_s, al_d, wedot + 8, bufB, b2,
                                            lng, lnb, outp, N);
}

// Round 7
// 299.420 us; speedup vs baseline: 1.6973x; 1.0399x over previous
//
#include <hip/hip_runtime.h>
#include <hip/hip_bf16.h>
#include <math.h>

// GAT x3 + LayerNorm for MI355X (gfx950).
// R7: two nodes per wave in aggregation (2 independent gather chains/wave),
// single-pass block scan, launches merged 19->11 (prep_kernel builds Wf1/Wf2/
// wedot/va0 in one dispatch; dots0 fused into gemm0; scatter+selfloop merged).
// Carried: bf16 h end-to-end, al = A @ va via extra MFMA col-tile, inline exp
// weights, int2 edge records.

typedef __attribute__((ext_vector_type(8))) short short8;
typedef __attribute__((ext_vector_type(4))) float float4v;

__device__ __forceinline__ float wave_sum(float v) {
#pragma unroll
  for (int off = 32; off > 0; off >>= 1) v += __shfl_xor(v, off, 64);
  return v;
}

__device__ __forceinline__ unsigned short f2bf(float v) {
  unsigned u = __float_as_uint(v);
  unsigned r = u + 0x7fff + ((u >> 16) & 1);  // RNE
  return (unsigned short)(r >> 16);
}

__device__ __forceinline__ float bf2f(unsigned short u) {
  return __uint_as_float(((unsigned)u) << 16);
}

// leaky_relu(0.2) + clamp + exp (softmax max cancels in the ratio)
__device__ __forceinline__ float edge_w(float a) {
  a = fmaxf(a, 0.2f * a);
  a = fminf(a, 30.f);
  return __expf(a);
}

__global__ void deg_kernel(const int* __restrict__ dst, const float* __restrict__ eattr,
                           int* __restrict__ deg, float* __restrict__ asum, int E) {
  int e = blockIdx.x * 256 + threadIdx.x;
  if (e >= E) return;
  int d = dst[e];
  atomicAdd(&deg[d], 1);
  atomicAdd(&asum[d], eattr[e]);
}

// Single-pass scan: thread t owns C contiguous nodes; two cheap passes over deg.
__global__ __launch_bounds__(1024) void scan_kernel(const int* __restrict__ deg,
                                                    int* __restrict__ row_ptr, int n) {
  int tid = threadIdx.x, wid = tid >> 6, lane = tid & 63;
  int C = (n + 1023) >> 10;
  int base = tid * C;
  int sum = 0;
  for (int j = 0; j < C; j++) {
    int i = base + j;
    if (i < n) sum += deg[i] + 1;
  }
  int sc = sum;
#pragma unroll
  for (int off = 1; off < 64; off <<= 1) {
    int t = __shfl_up(sc, off, 64);
    if (lane >= off) sc += t;
  }
  __shared__ int wtot[16], wexc[16];
  __shared__ int total;
  if (lane == 63) wtot[wid] = sc;
  __syncthreads();
  if (tid == 0) {
    int run = 0;
#pragma unroll
    for (int i = 0; i < 16; i++) { int t = wtot[i]; wexc[i] = run; run += t; }
    total = run;
  }
  __syncthreads();
  int run = wexc[wid] + (sc - sum);
  for (int j = 0; j < C; j++) {
    int i = base + j;
    if (i < n) {
      row_ptr[i] = run;
      run += deg[i] + 1;
    }
  }
  if (tid == 0) row_ptr[n] = total;
}

// Merged CSR fill: t<E scatters real edges (atomic slot); t>=E appends the
// self loop (last slot in row, attr = mean of incoming).
__global__ void fill_kernel(const int* __restrict__ src, const int* __restrict__ dst,
                            const float* __restrict__ eattr, const int* __restrict__ row_ptr,
                            const int* __restrict__ deg, const float* __restrict__ asum,
                            int* __restrict__ fill, int2* __restrict__ edge, int E, int n) {
  int t = blockIdx.x * 256 + threadIdx.x;
  if (t < E) {
    int d = dst[t];
    int pos = row_ptr[d] + atomicAdd(&fill[d], 1);
    edge[pos] = make_int2(src[t], __float_as_int(eattr[t]));
  } else {
    int i = t - E;
    if (i < n) {
      int dg = deg[i];
      edge[row_ptr[i] + dg] = make_int2(i, __float_as_int(asum[i] / fmaxf((float)dg, 1.f)));
    }
  }
}

// One dispatch builds: Wf1 (17 tiles incl. inline va1), Wf2 (5 tiles incl.
// inline va2), wedot[0..8], va0[16x16].
// Fragment layout: idx=((nt*8+ks)*64+lane)*8+j ; k=ks*32+(lane>>4)*8+j ;
// col=lane&15. va tile: col<H -> W·a_s ; col<2H -> W·a_d ; else 0.
__global__ __launch_bounds__(256) void prep_kernel(
    const float* __restrict__ W0, const float* __restrict__ as0, const float* __restrict__ ad0,
    const float* __restrict__ We0, const float* __restrict__ ae0,
    const float* __restrict__ W1, const float* __restrict__ as1, const float* __restrict__ ad1,
    const float* __restrict__ We1, const float* __restrict__ ae1,
    const float* __restrict__ W2, const float* __restrict__ as2, const float* __restrict__ ad2,
    const float* __restrict__ We2, const float* __restrict__ ae2,
    unsigned short* __restrict__ Wf1, unsigned short* __restrict__ Wf2,
    float* __restrict__ wedot, float* __restrict__ va0) {
  int b = blockIdx.x;
  if (b < 272) {  // Wf1: 17*4096 = 69632 elems
    int idx = b * 256 + threadIdx.x;
    int j = idx & 7, lane = (idx >> 3) & 63, ks = (idx >> 9) & 7, nt = idx >> 12;
    int k = ks * 32 + (lane >> 4) * 8 + j;
    int col = lane & 15;
    float v = 0.f;
    if (nt < 16) {
      v = W1[(size_t)k * 256 + nt * 16 + col];
    } else if (col < 4) {
      for (int c = 0; c < 64; c++) v = fmaf(W1[(size_t)k * 256 + col * 64 + c], as1[col * 64 + c], v);
    } else if (col < 8) {
      int h = col - 4;
      for (int c = 0; c < 64; c++) v = fmaf(W1[(size_t)k * 256 + h * 64 + c], ad1[h * 64 + c], v);
    }
    Wf1[idx] = f2bf(v);
  } else if (b < 352) {  // Wf2: 5*4096 = 20480 elems
    int idx = (b - 272) * 256 + threadIdx.x;
    int j = idx & 7, lane = (idx >> 3) & 63, ks = (idx >> 9) & 7, nt = idx >> 12;
    int k = ks * 32 + (lane >> 4) * 8 + j;
    int col = lane & 15;
    float v = 0.f;
    if (nt < 4) {
      v = W2[(size_t)k * 64 + nt * 16 + col];
    } else if (col < 1) {
      for (int c = 0; c < 64; c++) v = fmaf(W2[(size_t)k * 64 + c], as2[c], v);
    } else if (col < 2) {
      for (int c = 0; c < 64; c++) v = fmaf(W2[(size_t)k * 64 + c], ad2[c], v);
    }
    Wf2[idx] = f2bf(v);
  } else if (b == 352) {  // wedot (wave 0 only)
    if (threadIdx.x >= 64) return;
    int c = threadIdx.x;
    for (int h = 0; h < 4; h++) {
      float v = wave_sum(We0[h * 64 + c] * ae0[h * 64 + c]);
      if (c == 0) wedot[h] = v;
    }
    for (int h = 0; h < 4; h++) {
      float v = wave_sum(We1[h * 64 + c] * ae1[h * 64 + c]);
      if (c == 0) wedot[4 + h] = v;
    }
    float v = wave_sum(We2[c] * ae2[c]);
    if (c == 0) wedot[8] = v;
  } else {  // va0: 16x16
    int col = threadIdx.x & 15, k = threadIdx.x >> 4;
    float v = 0.f;
    if (col < 4) {
      for (int c = 0; c < 64; c++) v = fmaf(W0[(size_t)k * 256 + col * 64 + c], as0[col * 64 + c], v);
    } else if (col < 8) {
      int h = col - 4;
      for (int c = 0; c < 64; c++) v = fmaf(W0[(size_t)k * 256 + h * 64 + c], ad0[h * 64 + c], v);
    }
    va0[threadIdx.x] = v;
  }
}

// f32 GEMM for layer 0 (K=16): bf16 out; layer-0 attention dots fused
// (x tile is already in LDS; al = x @ va0, f32-exact).
template <int K, int M>
__global__ __launch_bounds__(256) void gemm0_kernel(const float* __restrict__ in,
                                                    const float* __restrict__ W,
                                                    const float* __restrict__ va0,
                                                    unsigned short* __restrict__ out,
                                                    float* __restrict__ al_s,
                                                    float* __restrict__ al_d, int n) {
  constexpr int CT = M / 64;
  constexpr int ROWS = 16;
  constexpr int T = 4;
  __shared__ float4 lds[ROWS * K / 4];
  int row0 = blockIdx.x * ROWS;
  int tid = threadIdx.x;
  int total4 = ROWS * K / 4;
  const float4* in4 = (const float4*)(in + (size_t)row0 * K);
  if (row0 + ROWS <= n) {
    for (int i = tid; i < total4; i += 256) lds[i] = in4[i];
  } else {
    float4 z = make_float4(0.f, 0.f, 0.f, 0.f);
    for (int i = tid; i < total4; i += 256) {
      int r = row0 + (i * 4) / K;
      lds[i] = (r < n) ? in4[i] : z;
    }
  }
  __syncthreads();
  int c0 = tid & 63;
  int rg = tid >> 6;
  float acc[T][CT];
#pragma unroll
  for (int t = 0; t < T; t++)
#pragma unroll
    for (int c = 0; c < CT; c++) acc[t][c] = 0.f;

#pragma unroll
  for (int k4 = 0; k4 < K; k4 += 4) {
    float wv[4][CT];
#pragma unroll
    for (int kk = 0; kk < 4; kk++)
#pragma unroll
      for (int c = 0; c < CT; c++) wv[kk][c] = W[(size_t)(k4 + kk) * M + c0 + 64 * c];
#pragma unroll
    for (int t = 0; t < T; t++) {
      float4 xv = lds[(rg * T + t) * (K / 4) + (k4 >> 2)];
      const float* xs = (const float*)&xv;
#pragma unroll
      for (int kk = 0; kk < 4; kk++)
#pragma unroll
        for (int c = 0; c < CT; c++) acc[t][c] = fmaf(xs[kk], wv[kk][c], acc[t][c]);
    }
  }
#pragma unroll
  for (int t = 0; t < T; t++) {
    int r = row0 + rg * T + t;
    if (r < n) {
#pragma unroll
      for (int c = 0; c < CT; c++) out[(size_t)r * M + c0 + 64 * c] = f2bf(acc[t][c]);
    }
  }
  // fused layer-0 dots: tid<128 -> (row, col) ; col<4 al_s, col in [4,8) al_d
  if (tid < 128) {
    int r = tid >> 3, col = tid & 7;
    const float* xr = (const float*)lds + r * K;
    float a = 0.f;
#pragma unroll
    for (int k = 0; k < K; k++) a = fmaf(xr[k], va0[k * 16 + col], a);
    int rr = row0 + r;
    if (rr < n) {
      if (col < 4) al_s[(size_t)rr * 4 + col] = a;
      else al_d[(size_t)rr * 4 + (col - 4)] = a;
    }
  }
}

// bf16 MFMA GEMM (K=256): bf16 out; al_s/al_d from the extra va col-tile
// (C-layout direct stores, no shuffles). One wave per 16-row strip.
template <int M, int H>
__global__ __launch_bounds__(64) void mfma_gemm_dots(
    const unsigned short* __restrict__ Abf, const unsigned short* __restrict__ Wfrag,
    unsigned short* __restrict__ out, float* __restrict__ al_s, float* __restrict__ al_d,
    int n) {
  int lane = threadIdx.x;
  int row0 = blockIdx.x * 16;
  int m = lane & 15, q = lane >> 4;

  short8 afrag[8];
  int r = row0 + m;
  if (r < n) {
    const short8* arow = (const short8*)(Abf + (size_t)r * 256);
#pragma unroll
    for (int ks = 0; ks < 8; ks++) afrag[ks] = arow[ks * 4 + q];
  } else {
#pragma unroll
    for (int ks = 0; ks < 8; ks++) afrag[ks] = (short8)0;
  }

  const short8* wf = (const short8*)Wfrag;

  auto epi = [&](int tile, float4v acc) {
    int col = tile * 16 + m;
#pragma unroll
    for (int reg = 0; reg < 4; reg++) {
      int rr = row0 + q * 4 + reg;
      if (rr < n) out[(size_t)rr * M + col] = f2bf(acc[reg]);
    }
  };

  for (int nt = 0; nt < M / 16; nt += 2) {
    const short8* b0 = wf + (size_t)nt * 8 * 64 + lane;
    const short8* b1 = b0 + 8 * 64;
    short8 bf0[8], bf1[8];
#pragma unroll
    for (int ks = 0; ks < 8; ks++) {
      bf0[ks] = b0[ks * 64];
      bf1[ks] = b1[ks * 64];
    }
    float4v acc0 = {0.f, 0.f, 0.f, 0.f};
    float4v acc1 = {0.f, 0.f, 0.f, 0.f};
#pragma unroll
    for (int ks = 0; ks < 8; ks++) {
      acc0 = __builtin_amdgcn_mfma_f32_16x16x32_bf16(afrag[ks], bf0[ks], acc0, 0, 0, 0);
      acc1 = __builtin_amdgcn_mfma_f32_16x16x32_bf16(afrag[ks], bf1[ks], acc1, 0, 0, 0);
    }
    epi(nt, acc0);
    epi(nt + 1, acc1);
  }

  // va tile -> al_s / al_d
  {
    const short8* bl = wf + (size_t)(M / 16) * 8 * 64 + lane;
    short8 bf[8];
#pragma unroll
    for (int ks = 0; ks < 8; ks++) bf[ks] = bl[ks * 64];
    float4v acc = {0.f, 0.f, 0.f, 0.f};
#pragma unroll
    for (int ks = 0; ks < 8; ks++)
      acc = __builtin_amdgcn_mfma_f32_16x16x32_bf16(afrag[ks], bf[ks], acc, 0, 0, 0);
#pragma unroll
    for (int reg = 0; reg < 4; reg++) {
      int rr = row0 + q * 4 + reg;
      if (rr < n) {
        if (m < H) al_s[(size_t)rr * H + m] = acc[reg];
        else if (m < 2 * H) al_d[(size_t)rr * H + (m - H)] = acc[reg];
      }
    }
  }
}

// H=4 aggregation: TWO nodes per wave (2 independent gather chains). Lane c
// holds channels 4c..4c+3, head = c>>4. B bf16. bias+ELU fused; bf16 out.
__global__ __launch_bounds__(256) void agg4_kernel(
    const int* __restrict__ row_ptr, const int2* __restrict__ edge,
    const float* __restrict__ al_s, const float* __restrict__ al_d,
    const float* __restrict__ wedot, const unsigned short* __restrict__ B,
    const float* __restrict__ bias, unsigned short* __restrict__ out, int n) {
  int wv = blockIdx.x * 4 + (threadIdx.x >> 6);
  int nodeA = wv * 2;
  if (nodeA >= n) return;
  int nodeB = nodeA + 1;
  bool hasB = nodeB < n;
  int c = threadIdx.x & 63;
  int h4 = c >> 4;
  float wd = wedot[h4];
  const ushort4* Bp = (const ushort4*)B;

  float adA = al_d[(size_t)nodeA * 4 + h4];
  int begA = row_ptr[nodeA], endA = row_ptr[nodeA + 1];
  float adB = 0.f;
  int endB = 0;
  if (hasB) {
    adB = al_d[(size_t)nodeB * 4 + h4];
    endB = row_ptr[nodeB + 1];
  }
  int begB = endA;  // rows are contiguous

  float4 accA = make_float4(0.f, 0.f, 0.f, 0.f), accB = make_float4(0.f, 0.f, 0.f, 0.f);
  float denA = 0.f, denB = 0.f;
  int eA = begA, eB = begB;

  auto consume = [&](int2 g, float al, ushort4 bv, float adn, float4& acc, float& den) {
    float w = edge_w(al + adn + __int_as_float(g.y) * wd);
    den += w;
    acc.x = fmaf(w, bf2f(bv.x), acc.x);
    acc.y = fmaf(w, bf2f(bv.y), acc.y);
    acc.z = fmaf(w, bf2f(bv.z), acc.z);
    acc.w = fmaf(w, bf2f(bv.w), acc.w);
  };

  // joint chunk-4 loop: 8 edge loads -> 8 al + 8 row loads -> consume
  while (eA + 4 <= endA && eB + 4 <= endB) {
    int2 gA[4], gB[4];
#pragma unroll
    for (int i = 0; i < 4; i++) gA[i] = edge[eA + i];
#pragma unroll
    for (int i = 0; i < 4; i++) gB[i] = edge[eB + i];
    float aA[4], aB[4];
#pragma unroll
    for (int i = 0; i < 4; i++) aA[i] = al_s[(size_t)gA[i].x * 4 + h4];
#pragma unroll
    for (int i = 0; i < 4; i++) aB[i] = al_s[(size_t)gB[i].x * 4 + h4];
    ushort4 bA[4], bB[4];
#pragma unroll
    for (int i = 0; i < 4; i++) bA[i] = Bp[(size_t)gA[i].x * 64 + c];
#pragma unroll
    for (int i = 0; i < 4; i++) bB[i] = Bp[(size_t)gB[i].x * 64 + c];
#pragma unroll
    for (int i = 0; i < 4; i++) consume(gA[i], aA[i], bA[i], adA, accA, denA);
#pragma unroll
    for (int i = 0; i < 4; i++) consume(gB[i], aB[i], bB[i], adB, accB, denB);
    eA += 4;
    eB += 4;
  }

  auto drain = [&](int e, int end, float adn, float4& acc, float& den) {
    for (; e + 4 <= end; e += 4) {
      int2 g[4];
      float a[4];
      ushort4 b[4];
#pragma unroll
      for (int i = 0; i < 4; i++) g[i] = edge[e + i];
#pragma unroll
      for (int i = 0; i < 4; i++) a[i] = al_s[(size_t)g[i].x * 4 + h4];
#pragma unroll
      for (int i = 0; i < 4; i++) b[i] = Bp[(size_t)g[i].x * 64 + c];
#pragma unroll
      for (int i = 0; i < 4; i++) consume(g[i], a[i], b[i], adn, acc, den);
    }
    for (; e < end; e++) {
      int2 g = edge[e];
      float a = al_s[(size_t)g.x * 4 + h4];
      ushort4 bv = Bp[(size_t)g.x * 64 + c];
      consume(g, a, bv, adn, acc, den);
    }
  };
  drain(eA, endA, adA, accA, denA);
  if (hasB) drain(eB, endB, adB, accB, denB);

  float4 b4 = ((const float4*)bias)[c];
  auto epi = [&](int node, float4 acc, float den) {
    float inv = 1.f / (den + 1e-16f);
    float ox = acc.x * inv + b4.x;
    float oy = acc.y * inv + b4.y;
    float oz = acc.z * inv + b4.z;
    float ow = acc.w * inv + b4.w;
    ox = ox > 0.f ? ox : expm1f(ox);
    oy = oy > 0.f ? oy : expm1f(oy);
    oz = oz > 0.f ? oz : expm1f(oz);
    ow = ow > 0.f ? ow : expm1f(ow);
    ushort4 o4;
    o4.x = f2bf(ox);
    o4.y = f2bf(oy);
    o4.z = f2bf(oz);
    o4.w = f2bf(ow);
    ((ushort4*)out)[(size_t)node * 64 + c] = o4;
  };
  epi(nodeA, accA, denA);
  if (hasB) epi(nodeB, accB, denB);
}

// H=1 aggregation + bias + LayerNorm fused: TWO nodes per wave, joint chunk-8.
__global__ __launch_bounds__(256) void agg_ln_kernel(
    const int* __restrict__ row_ptr, const int2* __restrict__ edge,
    const float* __restrict__ al_s, const float* __restrict__ al_d,
    const float* __restrict__ wedot, const unsigned short* __restrict__ B,
    const float* __restrict__ bias, const float* __restrict__ ln_g,
    const float* __restrict__ ln_b, float* __restrict__ out, int n) {
  int wv = blockIdx.x * 4 + (threadIdx.x >> 6);
  int nodeA = wv * 2;
  if (nodeA >= n) return;
  int nodeB = nodeA + 1;
  bool hasB = nodeB < n;
  int c = threadIdx.x & 63;
  float wd = wedot[0];

  float adA = al_d[nodeA];
  int begA = row_ptr[nodeA], endA = row_ptr[nodeA + 1];
  float adB = 0.f;
  int endB = 0;
  if (hasB) {
    adB = al_d[nodeB];
    endB = row_ptr[nodeB + 1];
  }
  int begB = endA;

  float accA = 0.f, denA = 0.f, accB = 0.f, denB = 0.f;
  int eA = begA, eB = begB;

  while (eA + 8 <= endA && eB + 8 <= endB) {
    int2 gA[8], gB[8];
#pragma unroll
    for (int i = 0; i < 8; i++) gA[i] = edge[eA + i];
#pragma unroll
    for (int i = 0; i < 8; i++) gB[i] = edge[eB + i];
    float aA[8], aB[8];
#pragma unroll
    for (int i = 0; i < 8; i++) aA[i] = al_s[gA[i].x];
#pragma unroll
    for (int i = 0; i < 8; i++) aB[i] = al_s[gB[i].x];
    unsigned short bA[8], bB[8];
#pragma unroll
    for (int i = 0; i < 8; i++) bA[i] = B[(size_t)gA[i].x * 64 + c];
#pragma unroll
    for (int i = 0; i < 8; i++) bB[i] = B[(size_t)gB[i].x * 64 + c];
#pragma unroll
    for (int i = 0; i < 8; i++) {
      float w = edge_w(aA[i] + adA + __int_as_float(gA[i].y) * wd);
      denA += w;
      accA = fmaf(w, bf2f(bA[i]), accA);
    }
#pragma unroll
    for (int i = 0; i < 8; i++) {
      float w = edge_w(aB[i] + adB + __int_as_float(gB[i].y) * wd);
      denB += w;
      accB = fmaf(w, bf2f(bB[i]), accB);
    }
    eA += 8;
    eB += 8;
  }

  auto drain = [&](int e, int end, float adn, float& acc, float& den) {
    for (; e + 4 <= end; e += 4) {
      int2 g[4];
      float a[4];
      unsigned short b[4];
#pragma unroll
      for (int i = 0; i < 4; i++) g[i] = edge[e + i];
#pragma unroll
      for (int i = 0; i < 4; i++) a[i] = al_s[g[i].x];
#pragma unroll
      for (int i = 0; i < 4; i++) b[i] = B[(size_t)g[i].x * 64 + c];
#pragma unroll
      for (int i = 0; i < 4; i++) {
        float w = edge_w(a[i] + adn + __int_as_float(g[i].y) * wd);
        den += w;
        acc = fmaf(w, bf2f(b[i]), acc);
      }
    }
    for (; e < end; e++) {
      int2 g = edge[e];
      float a = al_s[g.x];
      unsigned short bv = B[(size_t)g.x * 64 + c];
      float w = edge_w(a + adn + __int_as_float(g.y) * wd);
      den += w;
      acc = fmaf(w, bf2f(bv), acc);
    }
  };
  drain(eA, endA, adA, accA, denA);
  if (hasB) drain(eB, endB, adB, accB, denB);

  float gv = ln_g[c], bv2 = ln_b[c], bc = bias[c];
  auto epi = [&](int node, float acc, float den) {
    float o = acc / (den + 1e-16f) + bc;
    float mu = wave_sum(o) * (1.f / 64.f);
    float dv = o - mu;
    float var = wave_sum(dv * dv) * (1.f / 64.f);
    out[(size_t)node * 64 + c] = dv * rsqrtf(var + 1e-5f) * gv + bv2;
  };
  epi(nodeA, accA, denA);
  if (hasB) epi(nodeB, accB, denB);
}

extern "C" void kernel_launch(void* const* d_in, const int* in_sizes, int n_in,
                              void* d_out, int out_size, void* d_ws, size_t ws_size,
                              hipStream_t stream) {
  const float* x = (const float*)d_in[0];
  const int* ei = (const int*)d_in[1];
  const float* eattr = (const float*)d_in[2];
  const float* W0 = (const float*)d_in[3];
  const float* as0 = (const float*)d_in[4];
  const float* ad0 = (const float*)d_in[5];
  const float* We0 = (const float*)d_in[6];
  const float* ae0 = (const float*)d_in[7];
  const float* b0 = (const float*)d_in[8];
  const float* W1 = (const float*)d_in[9];
  const float* as1 = (const float*)d_in[10];
  const float* ad1 = (const float*)d_in[11];
  const float* We1 = (const float*)d_in[12];
  const float* ae1 = (const float*)d_in[13];
  const float* b1 = (const float*)d_in[14];
  const float* W2 = (const float*)d_in[15];
  const float* as2 = (const float*)d_in[16];
  const float* ad2 = (const float*)d_in[17];
  const float* We2 = (const float*)d_in[18];
  const float* ae2 = (const float*)d_in[19];
  const float* b2 = (const float*)d_in[20];
  const float* lng = (const float*)d_in[21];
  const float* lnb = (const float*)d_in[22];
  float* outp = (float*)d_out;

  const int N = in_sizes[0] / 16;
  const int E = in_sizes[1] / 2;
  const int P = E + N;
  const int* srcv = ei;
  const int* dstv = ei + E;

  char* w = (char*)d_ws;
  size_t off = 0;
  auto alloc = [&](size_t bytes) -> void* {
    void* p = w + off;
    off += (bytes + 255) & ~(size_t)255;
    return p;
  };
  int* deg = (int*)alloc((size_t)N * 4);
  float* asum = (float*)alloc((size_t)N * 4);
  int* fill = (int*)alloc((size_t)N * 4);
  size_t zero_bytes = off;
  int* row_ptr = (int*)alloc((size_t)(N + 1) * 4);
  int2* edge = (int2*)alloc((size_t)P * 8);
  float* wedot = (float*)alloc(16 * 4);
  float* al_s = (float*)alloc((size_t)N * 4 * 4);
  float* al_d = (float*)alloc((size_t)N * 4 * 4);
  float* va0 = (float*)alloc(16 * 16 * 4);
  unsigned short* Wf1 = (unsigned short*)alloc((size_t)17 * 4096 * 2);
  unsigned short* Wf2 = (unsigned short*)alloc((size_t)5 * 4096 * 2);
  unsigned short* bufA = (unsigned short*)alloc((size_t)N * 256 * 2);  // agg out
  unsigned short* bufB = (unsigned short*)alloc((size_t)N * 256 * 2);  // gemm out
  (void)ws_size;

  hipMemsetAsync(d_ws, 0, zero_bytes, stream);

  int gE = (E + 255) / 256;
  int gP = (P + 255) / 256;
  deg_kernel<<<gE, 256, 0, stream>>>(dstv, eattr, deg, asum, E);
  scan_kernel<<<1, 1024, 0, stream>>>(deg, row_ptr, N);
  fill_kernel<<<gP, 256, 0, stream>>>(srcv, dstv, eattr, row_ptr, deg, asum, fill, edge, E, N);
  prep_kernel<<<354, 256, 0, stream>>>(W0, as0, ad0, We0, ae0, W1, as1, ad1, We1, ae1,
                                       W2, as2, ad2, We2, ae2, Wf1, Wf2, wedot, va0);

  int gGemm0 = (N + 15) / 16;
  int gStrip = (N + 15) / 16;
  int gPair = (((N + 1) / 2) + 3) / 4;  // 2 nodes per wave, 4 waves per block

  // ---- layer 0
  gemm0_kernel<16, 256><<<gGemm0, 256, 0, stream>>>(x, W0, va0, bufB, al_s, al_d, N);
  agg4_kernel<<<gPair, 256, 0, stream>>>(row_ptr, edge, al_s, al_d, wedot, bufB, b0, bufA, N);

  // ---- layer 1
  mfma_gemm_dots<256, 4><<<gStrip, 64, 0, stream>>>(bufA, Wf1, bufB, al_s, al_d, N);
  agg4_kernel<<<gPair, 256, 0, stream>>>(row_ptr, edge, al_s, al_d, wedot + 4, bufB, b1, bufA, N);

  // ---- layer 2 (+ LayerNorm -> d_out)
  mfma_gemm_dots<64, 1><<<gStrip, 64, 0, stream>>>(bufA, Wf2, bufB, al_s, al_d, N);
  agg_ln_kernel<<<gPair, 256, 0, stream>>>(row_ptr, edge, al_s, al_d, wedot + 8, bufB, b2,
                                           lng, lnb, outp, N);
}

// Round 8
// 286.856 us; speedup vs baseline: 1.7716x; 1.0438x over previous
//
#include <hip/hip_runtime.h>
#include <hip/hip_bf16.h>
#include <math.h>

// GAT x3 + LayerNorm for MI355X (gfx950).
// R8: aggregation restructured for gather-instruction throughput: one wave =
// one node with 2 edge streams (agg4: 32 lanes x ushort8 -> one dwordx4 instr
// fetches TWO 512B rows) / 4 edge streams (agg_ln: 16 lanes x ushort4 -> one
// instr fetches FOUR 128B rows). Streams recombined by shfl_xor at the end.
// Carried: bf16 h end-to-end, al = A @ va via extra MFMA col-tile, inline exp
// weights, int2 edge records, merged prep, single-pass scan.

typedef __attribute__((ext_vector_type(8))) short short8;
typedef __attribute__((ext_vector_type(4))) float float4v;

__device__ __forceinline__ float wave_sum(float v) {
#pragma unroll
  for (int off = 32; off > 0; off >>= 1) v += __shfl_xor(v, off, 64);
  return v;
}

__device__ __forceinline__ unsigned short f2bf(float v) {
  unsigned u = __float_as_uint(v);
  unsigned r = u + 0x7fff + ((u >> 16) & 1);  // RNE
  return (unsigned short)(r >> 16);
}

__device__ __forceinline__ float bf2f(unsigned short u) {
  return __uint_as_float(((unsigned)u) << 16);
}

// leaky_relu(0.2) + clamp + exp (softmax max cancels in the ratio)
__device__ __forceinline__ float edge_w(float a) {
  a = fmaxf(a, 0.2f * a);
  a = fminf(a, 30.f);
  return __expf(a);
}

__global__ void deg_kernel(const int* __restrict__ dst, const float* __restrict__ eattr,
                           int* __restrict__ deg, float* __restrict__ asum, int E) {
  int e = blockIdx.x * 256 + threadIdx.x;
  if (e >= E) return;
  int d = dst[e];
  atomicAdd(&deg[d], 1);
  atomicAdd(&asum[d], eattr[e]);
}

// Single-pass scan: thread t owns C contiguous nodes; two cheap passes over deg.
__global__ __launch_bounds__(1024) void scan_kernel(const int* __restrict__ deg,
                                                    int* __restrict__ row_ptr, int n) {
  int tid = threadIdx.x, wid = tid >> 6, lane = tid & 63;
  int C = (n + 1023) >> 10;
  int base = tid * C;
  int sum = 0;
  for (int j = 0; j < C; j++) {
    int i = base + j;
    if (i < n) sum += deg[i] + 1;
  }
  int sc = sum;
#pragma unroll
  for (int off = 1; off < 64; off <<= 1) {
    int t = __shfl_up(sc, off, 64);
    if (lane >= off) sc += t;
  }
  __shared__ int wtot[16], wexc[16];
  __shared__ int total;
  if (lane == 63) wtot[wid] = sc;
  __syncthreads();
  if (tid == 0) {
    int run = 0;
#pragma unroll
    for (int i = 0; i < 16; i++) { int t = wtot[i]; wexc[i] = run; run += t; }
    total = run;
  }
  __syncthreads();
  int run = wexc[wid] + (sc - sum);
  for (int j = 0; j < C; j++) {
    int i = base + j;
    if (i < n) {
      row_ptr[i] = run;
      run += deg[i] + 1;
    }
  }
  if (tid == 0) row_ptr[n] = total;
}

// Merged CSR fill: t<E scatters real edges (atomic slot); t>=E appends the
// self loop (last slot in row, attr = mean of incoming).
__global__ void fill_kernel(const int* __restrict__ src, const int* __restrict__ dst,
                            const float* __restrict__ eattr, const int* __restrict__ row_ptr,
                            const int* __restrict__ deg, const float* __restrict__ asum,
                            int* __restrict__ fill, int2* __restrict__ edge, int E, int n) {
  int t = blockIdx.x * 256 + threadIdx.x;
  if (t < E) {
    int d = dst[t];
    int pos = row_ptr[d] + atomicAdd(&fill[d], 1);
    edge[pos] = make_int2(src[t], __float_as_int(eattr[t]));
  } else {
    int i = t - E;
    if (i < n) {
      int dg = deg[i];
      edge[row_ptr[i] + dg] = make_int2(i, __float_as_int(asum[i] / fmaxf((float)dg, 1.f)));
    }
  }
}

// One dispatch builds: Wf1 (17 tiles incl. inline va1), Wf2 (5 tiles incl.
// inline va2), wedot[0..8], va0[16x16].
__global__ __launch_bounds__(256) void prep_kernel(
    const float* __restrict__ W0, const float* __restrict__ as0, const float* __restrict__ ad0,
    const float* __restrict__ We0, const float* __restrict__ ae0,
    const float* __restrict__ W1, const float* __restrict__ as1, const float* __restrict__ ad1,
    const float* __restrict__ We1, const float* __restrict__ ae1,
    const float* __restrict__ W2, const float* __restrict__ as2, const float* __restrict__ ad2,
    const float* __restrict__ We2, const float* __restrict__ ae2,
    unsigned short* __restrict__ Wf1, unsigned short* __restrict__ Wf2,
    float* __restrict__ wedot, float* __restrict__ va0) {
  int b = blockIdx.x;
  if (b < 272) {  // Wf1: 17*4096 elems
    int idx = b * 256 + threadIdx.x;
    int j = idx & 7, lane = (idx >> 3) & 63, ks = (idx >> 9) & 7, nt = idx >> 12;
    int k = ks * 32 + (lane >> 4) * 8 + j;
    int col = lane & 15;
    float v = 0.f;
    if (nt < 16) {
      v = W1[(size_t)k * 256 + nt * 16 + col];
    } else if (col < 4) {
      for (int c = 0; c < 64; c++) v = fmaf(W1[(size_t)k * 256 + col * 64 + c], as1[col * 64 + c], v);
    } else if (col < 8) {
      int h = col - 4;
      for (int c = 0; c < 64; c++) v = fmaf(W1[(size_t)k * 256 + h * 64 + c], ad1[h * 64 + c], v);
    }
    Wf1[idx] = f2bf(v);
  } else if (b < 352) {  // Wf2: 5*4096 elems
    int idx = (b - 272) * 256 + threadIdx.x;
    int j = idx & 7, lane = (idx >> 3) & 63, ks = (idx >> 9) & 7, nt = idx >> 12;
    int k = ks * 32 + (lane >> 4) * 8 + j;
    int col = lane & 15;
    float v = 0.f;
    if (nt < 4) {
      v = W2[(size_t)k * 64 + nt * 16 + col];
    } else if (col < 1) {
      for (int c = 0; c < 64; c++) v = fmaf(W2[(size_t)k * 64 + c], as2[c], v);
    } else if (col < 2) {
      for (int c = 0; c < 64; c++) v = fmaf(W2[(size_t)k * 64 + c], ad2[c], v);
    }
    Wf2[idx] = f2bf(v);
  } else if (b == 352) {  // wedot (wave 0 only)
    if (threadIdx.x >= 64) return;
    int c = threadIdx.x;
    for (int h = 0; h < 4; h++) {
      float v = wave_sum(We0[h * 64 + c] * ae0[h * 64 + c]);
      if (c == 0) wedot[h] = v;
    }
    for (int h = 0; h < 4; h++) {
      float v = wave_sum(We1[h * 64 + c] * ae1[h * 64 + c]);
      if (c == 0) wedot[4 + h] = v;
    }
    float v = wave_sum(We2[c] * ae2[c]);
    if (c == 0) wedot[8] = v;
  } else {  // va0: 16x16
    int col = threadIdx.x & 15, k = threadIdx.x >> 4;
    float v = 0.f;
    if (col < 4) {
      for (int c = 0; c < 64; c++) v = fmaf(W0[(size_t)k * 256 + col * 64 + c], as0[col * 64 + c], v);
    } else if (col < 8) {
      int h = col - 4;
      for (int c = 0; c < 64; c++) v = fmaf(W0[(size_t)k * 256 + h * 64 + c], ad0[h * 64 + c], v);
    }
    va0[threadIdx.x] = v;
  }
}

// f32 GEMM for layer 0 (K=16): bf16 out; layer-0 attention dots fused.
template <int K, int M>
__global__ __launch_bounds__(256) void gemm0_kernel(const float* __restrict__ in,
                                                    const float* __restrict__ W,
                                                    const float* __restrict__ va0,
                                                    unsigned short* __restrict__ out,
                                                    float* __restrict__ al_s,
                                                    float* __restrict__ al_d, int n) {
  constexpr int CT = M / 64;
  constexpr int ROWS = 16;
  constexpr int T = 4;
  __shared__ float4 lds[ROWS * K / 4];
  int row0 = blockIdx.x * ROWS;
  int tid = threadIdx.x;
  int total4 = ROWS * K / 4;
  const float4* in4 = (const float4*)(in + (size_t)row0 * K);
  if (row0 + ROWS <= n) {
    for (int i = tid; i < total4; i += 256) lds[i] = in4[i];
  } else {
    float4 z = make_float4(0.f, 0.f, 0.f, 0.f);
    for (int i = tid; i < total4; i += 256) {
      int r = row0 + (i * 4) / K;
      lds[i] = (r < n) ? in4[i] : z;
    }
  }
  __syncthreads();
  int c0 = tid & 63;
  int rg = tid >> 6;
  float acc[T][CT];
#pragma unroll
  for (int t = 0; t < T; t++)
#pragma unroll
    for (int c = 0; c < CT; c++) acc[t][c] = 0.f;

#pragma unroll
  for (int k4 = 0; k4 < K; k4 += 4) {
    float wv[4][CT];
#pragma unroll
    for (int kk = 0; kk < 4; kk++)
#pragma unroll
      for (int c = 0; c < CT; c++) wv[kk][c] = W[(size_t)(k4 + kk) * M + c0 + 64 * c];
#pragma unroll
    for (int t = 0; t < T; t++) {
      float4 xv = lds[(rg * T + t) * (K / 4) + (k4 >> 2)];
      const float* xs = (const float*)&xv;
#pragma unroll
      for (int kk = 0; kk < 4; kk++)
#pragma unroll
        for (int c = 0; c < CT; c++) acc[t][c] = fmaf(xs[kk], wv[kk][c], acc[t][c]);
    }
  }
#pragma unroll
  for (int t = 0; t < T; t++) {
    int r = row0 + rg * T + t;
    if (r < n) {
#pragma unroll
      for (int c = 0; c < CT; c++) out[(size_t)r * M + c0 + 64 * c] = f2bf(acc[t][c]);
    }
  }
  // fused layer-0 dots: tid<128 -> (row, col) ; col<4 al_s, col in [4,8) al_d
  if (tid < 128) {
    int r = tid >> 3, col = tid & 7;
    const float* xr = (const float*)lds + r * K;
    float a = 0.f;
#pragma unroll
    for (int k = 0; k < K; k++) a = fmaf(xr[k], va0[k * 16 + col], a);
    int rr = row0 + r;
    if (rr < n) {
      if (col < 4) al_s[(size_t)rr * 4 + col] = a;
      else al_d[(size_t)rr * 4 + (col - 4)] = a;
    }
  }
}

// bf16 MFMA GEMM (K=256): bf16 out; al_s/al_d from the extra va col-tile.
template <int M, int H>
__global__ __launch_bounds__(64) void mfma_gemm_dots(
    const unsigned short* __restrict__ Abf, const unsigned short* __restrict__ Wfrag,
    unsigned short* __restrict__ out, float* __restrict__ al_s, float* __restrict__ al_d,
    int n) {
  int lane = threadIdx.x;
  int row0 = blockIdx.x * 16;
  int m = lane & 15, q = lane >> 4;

  short8 afrag[8];
  int r = row0 + m;
  if (r < n) {
    const short8* arow = (const short8*)(Abf + (size_t)r * 256);
#pragma unroll
    for (int ks = 0; ks < 8; ks++) afrag[ks] = arow[ks * 4 + q];
  } else {
#pragma unroll
    for (int ks = 0; ks < 8; ks++) afrag[ks] = (short8)0;
  }

  const short8* wf = (const short8*)Wfrag;

  auto epi = [&](int tile, float4v acc) {
    int col = tile * 16 + m;
#pragma unroll
    for (int reg = 0; reg < 4; reg++) {
      int rr = row0 + q * 4 + reg;
      if (rr < n) out[(size_t)rr * M + col] = f2bf(acc[reg]);
    }
  };

  for (int nt = 0; nt < M / 16; nt += 2) {
    const short8* b0 = wf + (size_t)nt * 8 * 64 + lane;
    const short8* b1 = b0 + 8 * 64;
    short8 bf0[8], bf1[8];
#pragma unroll
    for (int ks = 0; ks < 8; ks++) {
      bf0[ks] = b0[ks * 64];
      bf1[ks] = b1[ks * 64];
    }
    float4v acc0 = {0.f, 0.f, 0.f, 0.f};
    float4v acc1 = {0.f, 0.f, 0.f, 0.f};
#pragma unroll
    for (int ks = 0; ks < 8; ks++) {
      acc0 = __builtin_amdgcn_mfma_f32_16x16x32_bf16(afrag[ks], bf0[ks], acc0, 0, 0, 0);
      acc1 = __builtin_amdgcn_mfma_f32_16x16x32_bf16(afrag[ks], bf1[ks], acc1, 0, 0, 0);
    }
    epi(nt, acc0);
    epi(nt + 1, acc1);
  }

  // va tile -> al_s / al_d
  {
    const short8* bl = wf + (size_t)(M / 16) * 8 * 64 + lane;
    short8 bf[8];
#pragma unroll
    for (int ks = 0; ks < 8; ks++) bf[ks] = bl[ks * 64];
    float4v acc = {0.f, 0.f, 0.f, 0.f};
#pragma unroll
    for (int ks = 0; ks < 8; ks++)
      acc = __builtin_amdgcn_mfma_f32_16x16x32_bf16(afrag[ks], bf[ks], acc, 0, 0, 0);
#pragma unroll
    for (int reg = 0; reg < 4; reg++) {
      int rr = row0 + q * 4 + reg;
      if (rr < n) {
        if (m < H) al_s[(size_t)rr * H + m] = acc[reg];
        else if (m < 2 * H) al_d[(size_t)rr * H + (m - H)] = acc[reg];
      }
    }
  }
}

// H=4 aggregation: one wave per node, TWO edge streams; lanes 0-31 stream A,
// 32-63 stream B. Lane holds channels l*8..l*8+7 (ushort8 = one dwordx4 per
// 32 lanes -> ONE instruction fetches two 512B rows). Streams merged via
// shfl_xor(32). bias+ELU fused; bf16 out.
__global__ __launch_bounds__(256) void agg4_kernel(
    const int* __restrict__ row_ptr, const int2* __restrict__ edge,
    const float* __restrict__ al_s, const float* __restrict__ al_d,
    const float* __restrict__ wedot, const unsigned short* __restrict__ B,
    const float* __restrict__ bias, unsigned short* __restrict__ out, int n) {
  int node = blockIdx.x * 4 + (threadIdx.x >> 6);
  if (node >= n) return;
  int lane = threadIdx.x & 63;
  int half = lane >> 5;
  int l = lane & 31;   // channel group: channels l*8 .. l*8+7
  int h4 = l >> 3;     // head
  float wd = wedot[h4];
  float adn = al_d[(size_t)node * 4 + h4];
  int beg = row_ptr[node], end = row_ptr[node + 1];
  int cnt = end - beg;
  int cntA = (cnt + 1) >> 1;
  int myCnt = half ? (cnt - cntA) : cntA;
  int myBeg = half ? (beg + cntA) : beg;

  float acc[8];
#pragma unroll
  for (int j = 0; j < 8; j++) acc[j] = 0.f;
  float den = 0.f;

  int i = 0;
  for (; i + 4 <= cntA; i += 4) {
    int2 g[4];
    float als[4];
    short8 bv[4];
    bool val[4];
#pragma unroll
    for (int t = 0; t < 4; t++) {
      val[t] = (i + t) < myCnt;
      int e = val[t] ? (myBeg + i + t) : (end - 1);
      g[t] = edge[e];
    }
#pragma unroll
    for (int t = 0; t < 4; t++) als[t] = al_s[(size_t)g[t].x * 4 + h4];
#pragma unroll
    for (int t = 0; t < 4; t++) bv[t] = ((const short8*)(B + (size_t)g[t].x * 256))[l];
#pragma unroll
    for (int t = 0; t < 4; t++) {
      float w = edge_w(als[t] + adn + __int_as_float(g[t].y) * wd);
      w = val[t] ? w : 0.f;
      den += w;
      const unsigned short* bp = (const unsigned short*)&bv[t];
#pragma unroll
      for (int j = 0; j < 8; j++) acc[j] = fmaf(w, bf2f(bp[j]), acc[j]);
    }
  }
  for (; i < cntA; i++) {
    bool valid = i < myCnt;
    int e = valid ? (myBeg + i) : (end - 1);
    int2 g = edge[e];
    float als = al_s[(size_t)g.x * 4 + h4];
    short8 bv = ((const short8*)(B + (size_t)g.x * 256))[l];
    float w = edge_w(als + adn + __int_as_float(g.y) * wd);
    w = valid ? w : 0.f;
    den += w;
    const unsigned short* bp = (const unsigned short*)&bv;
#pragma unroll
    for (int j = 0; j < 8; j++) acc[j] = fmaf(w, bf2f(bp[j]), acc[j]);
  }

  // merge the two streams
  den += __shfl_xor(den, 32, 64);
#pragma unroll
  for (int j = 0; j < 8; j++) acc[j] += __shfl_xor(acc[j], 32, 64);

  if (half == 0) {
    float inv = 1.f / (den + 1e-16f);
    float4 b0 = ((const float4*)bias)[l * 2];
    float4 b1 = ((const float4*)bias)[l * 2 + 1];
    const float* bb = (const float*)&b0;
    unsigned short o8[8];
#pragma unroll
    for (int j = 0; j < 8; j++) {
      float bjv = (j < 4) ? ((const float*)&b0)[j] : ((const float*)&b1)[j - 4];
      float o = acc[j] * inv + bjv;
      o = o > 0.f ? o : expm1f(o);
      o8[j] = f2bf(o);
    }
    (void)bb;
    ((short8*)(out + (size_t)node * 256))[l] = *(short8*)o8;
  }
}

// H=1 aggregation + bias + LayerNorm: one wave per node, FOUR edge streams;
// 16 lanes each, lane holds channels l*4..l*4+3 (ushort4 -> one instruction
// fetches four 128B rows). Merge via shfl_xor(32), shfl_xor(16).
__global__ __launch_bounds__(256) void agg_ln_kernel(
    const int* __restrict__ row_ptr, const int2* __restrict__ edge,
    const float* __restrict__ al_s, const float* __restrict__ al_d,
    const float* __restrict__ wedot, const unsigned short* __restrict__ B,
    const float* __restrict__ bias, const float* __restrict__ ln_g,
    const float* __restrict__ ln_b, float* __restrict__ out, int n) {
  int node = blockIdx.x * 4 + (threadIdx.x >> 6);
  if (node >= n) return;
  int lane = threadIdx.x & 63;
  int q = lane >> 4;
  int l = lane & 15;  // channels l*4 .. l*4+3
  float wd = wedot[0];
  float adn = al_d[node];
  int beg = row_ptr[node], end = row_ptr[node + 1];
  int cnt = end - beg;
  int base = cnt >> 2, rem = cnt & 3;
  int myCnt = base + (q < rem ? 1 : 0);
  int myBeg = beg + q * base + min(q, rem);
  int iters = base + (rem ? 1 : 0);

  float4 acc = make_float4(0.f, 0.f, 0.f, 0.f);
  float den = 0.f;

  int i = 0;
  for (; i + 2 <= iters; i += 2) {
    int2 g[2];
    float als[2];
    ushort4 bv[2];
    bool val[2];
#pragma unroll
    for (int t = 0; t < 2; t++) {
      val[t] = (i + t) < myCnt;
      int e = val[t] ? (myBeg + i + t) : (end - 1);
      g[t] = edge[e];
    }
#pragma unroll
    for (int t = 0; t < 2; t++) als[t] = al_s[g[t].x];
#pragma unroll
    for (int t = 0; t < 2; t++) bv[t] = ((const ushort4*)(B + (size_t)g[t].x * 64))[l];
#pragma unroll
    for (int t = 0; t < 2; t++) {
      float w = edge_w(als[t] + adn + __int_as_float(g[t].y) * wd);
      w = val[t] ? w : 0.f;
      den += w;
      acc.x = fmaf(w, bf2f(bv[t].x), acc.x);
      acc.y = fmaf(w, bf2f(bv[t].y), acc.y);
      acc.z = fmaf(w, bf2f(bv[t].z), acc.z);
      acc.w = fmaf(w, bf2f(bv[t].w), acc.w);
    }
  }
  for (; i < iters; i++) {
    bool valid = i < myCnt;
    int e = valid ? (myBeg + i) : (end - 1);
    int2 g = edge[e];
    float als = al_s[g.x];
    ushort4 bv = ((const ushort4*)(B + (size_t)g.x * 64))[l];
    float w = edge_w(als + adn + __int_as_float(g.y) * wd);
    w = valid ? w : 0.f;
    den += w;
    acc.x = fmaf(w, bf2f(bv.x), acc.x);
    acc.y = fmaf(w, bf2f(bv.y), acc.y);
    acc.z = fmaf(w, bf2f(bv.z), acc.z);
    acc.w = fmaf(w, bf2f(bv.w), acc.w);
  }

  // merge the four streams
  den += __shfl_xor(den, 32, 64);
  den += __shfl_xor(den, 16, 64);
  acc.x += __shfl_xor(acc.x, 32, 64);
  acc.y += __shfl_xor(acc.y, 32, 64);
  acc.z += __shfl_xor(acc.z, 32, 64);
  acc.w += __shfl_xor(acc.w, 32, 64);
  acc.x += __shfl_xor(acc.x, 16, 64);
  acc.y += __shfl_xor(acc.y, 16, 64);
  acc.z += __shfl_xor(acc.z, 16, 64);
  acc.w += __shfl_xor(acc.w, 16, 64);

  float inv = 1.f / (den + 1e-16f);
  float4 b4 = ((const float4*)bias)[l];
  float4 o;
  o.x = acc.x * inv + b4.x;
  o.y = acc.y * inv + b4.y;
  o.z = acc.z * inv + b4.z;
  o.w = acc.w * inv + b4.w;
  float s = (o.x + o.y) + (o.z + o.w);
#pragma unroll
  for (int off = 1; off < 16; off <<= 1) s += __shfl_xor(s, off, 64);
  float mu = s * (1.f / 64.f);
  float dx = o.x - mu, dy = o.y - mu, dz = o.z - mu, dw = o.w - mu;
  float v = (dx * dx + dy * dy) + (dz * dz + dw * dw);
#pragma unroll
  for (int off = 1; off < 16; off <<= 1) v += __shfl_xor(v, off, 64);
  float rs = rsqrtf(v * (1.f / 64.f) + 1e-5f);
  if (q == 0) {
    float4 g4 = ((const float4*)ln_g)[l];
    float4 lb4 = ((const float4*)ln_b)[l];
    float4 r;
    r.x = dx * rs * g4.x + lb4.x;
    r.y = dy * rs * g4.y + lb4.y;
    r.z = dz * rs * g4.z + lb4.z;
    r.w = dw * rs * g4.w + lb4.w;
    ((float4*)(out + (size_t)node * 64))[l] = r;
  }
}

extern "C" void kernel_launch(void* const* d_in, const int* in_sizes, int n_in,
                              void* d_out, int out_size, void* d_ws, size_t ws_size,
                              hipStream_t stream) {
  const float* x = (const float*)d_in[0];
  const int* ei = (const int*)d_in[1];
  const float* eattr = (const float*)d_in[2];
  const float* W0 = (const float*)d_in[3];
  const float* as0 = (const float*)d_in[4];
  const float* ad0 = (const float*)d_in[5];
  const float* We0 = (const float*)d_in[6];
  const float* ae0 = (const float*)d_in[7];
  const float* b0 = (const float*)d_in[8];
  const float* W1 = (const float*)d_in[9];
  const float* as1 = (const float*)d_in[10];
  const float* ad1 = (const float*)d_in[11];
  const float* We1 = (const float*)d_in[12];
  const float* ae1 = (const float*)d_in[13];
  const float* b1 = (const float*)d_in[14];
  const float* W2 = (const float*)d_in[15];
  const float* as2 = (const float*)d_in[16];
  const float* ad2 = (const float*)d_in[17];
  const float* We2 = (const float*)d_in[18];
  const float* ae2 = (const float*)d_in[19];
  const float* b2 = (const float*)d_in[20];
  const float* lng = (const float*)d_in[21];
  const float* lnb = (const float*)d_in[22];
  float* outp = (float*)d_out;

  const int N = in_sizes[0] / 16;
  const int E = in_sizes[1] / 2;
  const int P = E + N;
  const int* srcv = ei;
  const int* dstv = ei + E;

  char* w = (char*)d_ws;
  size_t off = 0;
  auto alloc = [&](size_t bytes) -> void* {
    void* p = w + off;
    off += (bytes + 255) & ~(size_t)255;
    return p;
  };
  int* deg = (int*)alloc((size_t)N * 4);
  float* asum = (float*)alloc((size_t)N * 4);
  int* fill = (int*)alloc((size_t)N * 4);
  size_t zero_bytes = off;
  int* row_ptr = (int*)alloc((size_t)(N + 1) * 4);
  int2* edge = (int2*)alloc((size_t)P * 8);
  float* wedot = (float*)alloc(16 * 4);
  float* al_s = (float*)alloc((size_t)N * 4 * 4);
  float* al_d = (float*)alloc((size_t)N * 4 * 4);
  float* va0 = (float*)alloc(16 * 16 * 4);
  unsigned short* Wf1 = (unsigned short*)alloc((size_t)17 * 4096 * 2);
  unsigned short* Wf2 = (unsigned short*)alloc((size_t)5 * 4096 * 2);
  unsigned short* bufA = (unsigned short*)alloc((size_t)N * 256 * 2);  // agg out
  unsigned short* bufB = (unsigned short*)alloc((size_t)N * 256 * 2);  // gemm out
  (void)ws_size;

  hipMemsetAsync(d_ws, 0, zero_bytes, stream);

  int gE = (E + 255) / 256;
  int gP = (P + 255) / 256;
  deg_kernel<<<gE, 256, 0, stream>>>(dstv, eattr, deg, asum, E);
  scan_kernel<<<1, 1024, 0, stream>>>(deg, row_ptr, N);
  fill_kernel<<<gP, 256, 0, stream>>>(srcv, dstv, eattr, row_ptr, deg, asum, fill, edge, E, N);
  prep_kernel<<<354, 256, 0, stream>>>(W0, as0, ad0, We0, ae0, W1, as1, ad1, We1, ae1,
                                       W2, as2, ad2, We2, ae2, Wf1, Wf2, wedot, va0);

  int gGemm0 = (N + 15) / 16;
  int gStrip = (N + 15) / 16;
  int gNode4 = (N + 3) / 4;  // one node per wave, 4 waves per block

  // ---- layer 0
  gemm0_kernel<16, 256><<<gGemm0, 256, 0, stream>>>(x, W0, va0, bufB, al_s, al_d, N);
  agg4_kernel<<<gNode4, 256, 0, stream>>>(row_ptr, edge, al_s, al_d, wedot, bufB, b0, bufA, N);

  // ---- layer 1
  mfma_gemm_dots<256, 4><<<gStrip, 64, 0, stream>>>(bufA, Wf1, bufB, al_s, al_d, N);
  agg4_kernel<<<gNode4, 256, 0, stream>>>(row_ptr, edge, al_s, al_d, wedot + 4, bufB, b1, bufA, N);

  // ---- layer 2 (+ LayerNorm -> d_out)
  mfma_gemm_dots<64, 1><<<gStrip, 64, 0, stream>>>(bufA, Wf2, bufB, al_s, al_d, N);
  agg_ln_kernel<<<gNode4, 256, 0, stream>>>(row_ptr, edge, al_s, al_d, wedot + 8, bufB, b2,
                                            lng, lnb, outp, N);
}